// Round 4
// baseline (657.119 us; speedup 1.0000x reference)
//
#include <hip/hip_runtime.h>
#include <math.h>

// ---------------------------------------------------------------------------
// TemporalGNN round 4 == round 3 resubmit (round-3 bench was an infra
// failure: "container failed twice", no pytest/counter output; source
// re-audited for OOB/LDS/aliasing hazards — none found).
//  - aggregate-then-transform (GCN linearity): gather runs on the INPUT of
//    each conv (64-dim for conv1), GEMM writes the activation directly with
//    fused bias(+relu). H buffer eliminated.
//  - GEMM: full-W LDS staging, ONE barrier, no chunk loop; 32-row tile;
//    8 rows x 2 cols per thread; GEMM2 in-place (reads precede barrier).
//  - gathers vectorized (float2 rows for 128-dim).
// ws: [dinv][cnt][off][bsums][csr_src][csr_w][flags][numUsers]
//     [A1: n*128] [P1: n*64][pad: n*64]  (P2/A2 = P1 base, spans P1+pad)
// ---------------------------------------------------------------------------

#define HDIM 128

__global__ __launch_bounds__(256) void init_kernel(int* __restrict__ cnt,
                                                   int* __restrict__ flags,
                                                   int* __restrict__ off, int n, int e) {
    int i = blockIdx.x * 256 + threadIdx.x;
    if (i < n) cnt[i] = 0;
    if (i < 2048) flags[i] = 0;
    if (i == 0) off[n] = e;
}

__global__ __launch_bounds__(256) void hist_kernel(const int* __restrict__ dst,
                                                   int* __restrict__ cnt, int e) {
    int i = blockIdx.x * 256 + threadIdx.x;
    int stride = gridDim.x * 256;
    for (; i < e; i += stride) atomicAdd(&cnt[dst[i]], 1);
}

__global__ __launch_bounds__(256) void dinv_kernel(const int* __restrict__ cnt,
                                                   float* __restrict__ dinv, int n) {
    int i = blockIdx.x * 256 + threadIdx.x;
    if (i < n) dinv[i] = rsqrtf((float)cnt[i] + 1.0f);  // +1 = self-loop
}

// ---- exclusive scan over cnt[0..n) -> off, cursor ----
__global__ __launch_bounds__(256) void scan_blocksums(const int* __restrict__ cnt,
                                                      int* __restrict__ bsums, int n) {
    int base = blockIdx.x * 1024, t = threadIdx.x;
    int s = 0;
#pragma unroll
    for (int j = 0; j < 4; ++j) { int i = base + t * 4 + j; if (i < n) s += cnt[i]; }
    __shared__ int red[256];
    red[t] = s; __syncthreads();
    for (int o = 128; o; o >>= 1) { if (t < o) red[t] += red[t + o]; __syncthreads(); }
    if (t == 0) bsums[blockIdx.x] = red[0];
}

__global__ __launch_bounds__(256) void scan_top(int* __restrict__ bsums, int nb) {
    __shared__ int sh[256];
    int t = threadIdx.x;
    int v = (t < nb) ? bsums[t] : 0;
    sh[t] = v; __syncthreads();
    for (int o = 1; o < 256; o <<= 1) {
        int u = (t >= o) ? sh[t - o] : 0;
        __syncthreads();
        sh[t] += u;
        __syncthreads();
    }
    if (t < nb) bsums[t] = sh[t] - v;  // exclusive
}

__global__ __launch_bounds__(256) void scan_final(const int* __restrict__ cnt,
                                                  const int* __restrict__ bsums,
                                                  int* __restrict__ off,
                                                  int* cursor, int n) {
    int base = blockIdx.x * 1024, t = threadIdx.x;
    int v[4]; int s = 0;
#pragma unroll
    for (int j = 0; j < 4; ++j) { int i = base + t * 4 + j; v[j] = (i < n) ? cnt[i] : 0; s += v[j]; }
    __shared__ int sh[256];
    sh[t] = s; __syncthreads();
    for (int o = 1; o < 256; o <<= 1) {
        int u = (t >= o) ? sh[t - o] : 0;
        __syncthreads();
        sh[t] += u;
        __syncthreads();
    }
    int p = bsums[blockIdx.x] + (sh[t] - s);
#pragma unroll
    for (int j = 0; j < 4; ++j) {
        int i = base + t * 4 + j;
        if (i < n) { off[i] = p; cursor[i] = p; p += v[j]; }
    }
}

__global__ __launch_bounds__(256) void build_csr(const int* __restrict__ src,
                                                 const int* __restrict__ dst,
                                                 const float* __restrict__ dinv,
                                                 int* __restrict__ cursor,
                                                 int* __restrict__ csr_src,
                                                 float* __restrict__ csr_w, int e) {
    int i = blockIdx.x * 256 + threadIdx.x;
    int stride = gridDim.x * 256;
    for (; i < e; i += stride) {
        int s = src[i], d = dst[i];
        int p = atomicAdd(&cursor[d], 1);
        csr_src[p] = s;
        csr_w[p] = dinv[s] * dinv[d];
    }
}

// ---- pre-aggregation (gather side, runs on conv INPUT, D = 64 or 128) ----
// P[d] = dinv[d]^2 * X[d] + sum_{in-edges} w * X[src]
template <int D>
__global__ __launch_bounds__(256) void gather_pre(const int* __restrict__ off,
                                                  const int* __restrict__ csr_src,
                                                  const float* __restrict__ csr_w,
                                                  const float* __restrict__ dinv,
                                                  const float* __restrict__ X,
                                                  float* __restrict__ P, int n) {
    const int lane = threadIdx.x & 63;
    const int d = blockIdx.x * 4 + (threadIdx.x >> 6);
    if (d >= n) return;

    const float di = dinv[d];
    const float sl = di * di;
    const int p0 = off[d], p1 = off[d + 1];

    if (D == 64) {
        float a = X[(size_t)d * 64 + lane] * sl;
        for (int p = p0; p < p1; ++p) {
            int s = csr_src[p];
            float w = csr_w[p];
            a = fmaf(X[(size_t)s * 64 + lane], w, a);
        }
        P[(size_t)d * 64 + lane] = a;
    } else {
        const float2* X2 = (const float2*)X;
        float2 a = X2[(size_t)d * 64 + lane];
        a.x *= sl; a.y *= sl;
        for (int p = p0; p < p1; ++p) {
            int s = csr_src[p];
            float w = csr_w[p];
            float2 v = X2[(size_t)s * 64 + lane];
            a.x = fmaf(v.x, w, a.x);
            a.y = fmaf(v.y, w, a.y);
        }
        ((float2*)P)[(size_t)d * 64 + lane] = a;
    }
}

// ---- GEMM: out = X @ W + bias (X: n x K, W: K x 128), optional relu ----
// Full W staged once; single barrier; X/out may ALIAS (in-place): all X
// reads happen in staging before the barrier, all writes after.
template <int K, bool RELU>
__global__ __launch_bounds__(256) void gcn_gemm(const float* X,
                                                const float* __restrict__ W,
                                                const float* __restrict__ bias,
                                                float* out, int n) {
    __shared__ float wl[K * 128];   // 32 KB (K=64) / 64 KB (K=128)
    __shared__ float xl[32 * K];    // 8 KB / 16 KB

    const int tid = threadIdx.x;
    const int lane = tid & 63;
    const int wid = tid >> 6;
    const int rowBase = blockIdx.x * 32;
    const float bj0 = bias[lane];
    const float bj1 = bias[lane + 64];

    // stage X tile (contiguous 32*K block) and full W, vectorized
    {
        const float4* Xs = (const float4*)(X + (size_t)rowBase * K);
        float4* xl4 = (float4*)xl;
        const int xcnt = 32 * K / 4;
        for (int i = tid; i < xcnt; i += 256) xl4[i] = Xs[i];
        const float4* Ws = (const float4*)W;
        float4* wl4 = (float4*)wl;
        const int wcnt = K * 128 / 4;
        for (int i = tid; i < wcnt; i += 256) wl4[i] = Ws[i];
    }
    __syncthreads();

    float acc0[8] = {}, acc1[8] = {};
#pragma unroll 4
    for (int k2 = 0; k2 < K; k2 += 4) {
        float w00 = wl[(k2 + 0) * 128 + lane];
        float w01 = wl[(k2 + 0) * 128 + 64 + lane];
        float w10 = wl[(k2 + 1) * 128 + lane];
        float w11 = wl[(k2 + 1) * 128 + 64 + lane];
        float w20 = wl[(k2 + 2) * 128 + lane];
        float w21 = wl[(k2 + 2) * 128 + 64 + lane];
        float w30 = wl[(k2 + 3) * 128 + lane];
        float w31 = wl[(k2 + 3) * 128 + 64 + lane];
#pragma unroll
        for (int r = 0; r < 8; ++r) {
            const float4 x4 = *(const float4*)&xl[(wid * 8 + r) * K + k2];
            acc0[r] = fmaf(x4.x, w00, acc0[r]);
            acc1[r] = fmaf(x4.x, w01, acc1[r]);
            acc0[r] = fmaf(x4.y, w10, acc0[r]);
            acc1[r] = fmaf(x4.y, w11, acc1[r]);
            acc0[r] = fmaf(x4.z, w20, acc0[r]);
            acc1[r] = fmaf(x4.z, w21, acc1[r]);
            acc0[r] = fmaf(x4.w, w30, acc0[r]);
            acc1[r] = fmaf(x4.w, w31, acc1[r]);
        }
    }

#pragma unroll
    for (int r = 0; r < 8; ++r) {
        int row = rowBase + wid * 8 + r;
        if (row < n) {
            float v0 = acc0[r] + bj0;
            float v1 = acc1[r] + bj1;
            if (RELU) { v0 = fmaxf(v0, 0.f); v1 = fmaxf(v1, 0.f); }
            out[(size_t)row * HDIM + lane] = v0;
            out[(size_t)row * HDIM + 64 + lane] = v1;
        }
    }
}

__global__ __launch_bounds__(256) void mark_kernel(const int* __restrict__ items,
                                                   int* __restrict__ flags, int b) {
    int i = blockIdx.x * 256 + threadIdx.x;
    if (i < b) flags[items[i]] = 1;
}

__global__ __launch_bounds__(256) void count_kernel(const int* __restrict__ flags,
                                                    int* __restrict__ numUsers, int n) {
    __shared__ int sred[4];
    int tid = threadIdx.x;
    int s = 0;
    for (int i = tid; i < 2048; i += 256) s += flags[i];
    for (int m = 32; m; m >>= 1) s += __shfl_xor(s, m, 64);
    if ((tid & 63) == 0) sred[tid >> 6] = s;
    __syncthreads();
    if (tid == 0) *numUsers = n - (sred[0] + sred[1] + sred[2] + sred[3]);
}

#define MLP_ROWS 8
__global__ __launch_bounds__(256) void mlp_kernel(
    const float* __restrict__ h, const int* __restrict__ users,
    const int* __restrict__ items, const int* __restrict__ numUsersPtr,
    const float* __restrict__ fc1w, const float* __restrict__ fc1b,
    const float* __restrict__ fc2w, const float* __restrict__ fc2b,
    const float* __restrict__ outw, const float* __restrict__ outb,
    float* __restrict__ out, int bsize) {
    __shared__ float zl[4][MLP_ROWS][256];
    __shared__ float a1l[4][MLP_ROWS][64];

    const int tid = threadIdx.x;
    const int lane = tid & 63;
    const int wid = tid >> 6;
    const int nu = *numUsersPtr;
    const int wavesTotal = (gridDim.x * 256) >> 6;
    const int gw = (blockIdx.x * 256 + tid) >> 6;
    const float f1b = fc1b[lane];
    const float ob = outb[0];
    const float2* h2 = (const float2*)h;

    for (int base = gw * MLP_ROWS; base < bsize; base += wavesTotal * MLP_ROWS) {
#pragma unroll
        for (int r = 0; r < MLP_ROWS; ++r) {
            int row = base + r;
            if (row < bsize) {
                int u = users[row];
                int it = nu + items[row];
                float2 uv = h2[(size_t)u * 64 + lane];
                float2 iv = h2[(size_t)it * 64 + lane];
                *(float2*)&zl[wid][r][2 * lane] = uv;
                *(float2*)&zl[wid][r][128 + 2 * lane] = iv;
            }
        }
        float acc[MLP_ROWS];
#pragma unroll
        for (int r = 0; r < MLP_ROWS; ++r) acc[r] = f1b;
        for (int k = 0; k < 256; k += 4) {
            float w0 = fc1w[k * 64 + lane];
            float w1 = fc1w[(k + 1) * 64 + lane];
            float w2 = fc1w[(k + 2) * 64 + lane];
            float w3 = fc1w[(k + 3) * 64 + lane];
#pragma unroll
            for (int r = 0; r < MLP_ROWS; ++r) {
                const float4 z4 = *(const float4*)&zl[wid][r][k];
                acc[r] = fmaf(z4.x, w0, acc[r]);
                acc[r] = fmaf(z4.y, w1, acc[r]);
                acc[r] = fmaf(z4.z, w2, acc[r]);
                acc[r] = fmaf(z4.w, w3, acc[r]);
            }
        }
#pragma unroll
        for (int r = 0; r < MLP_ROWS; ++r) a1l[wid][r][lane] = fmaxf(acc[r], 0.f);

        const int half = lane >> 5, j = lane & 31;
        for (int rp = 0; rp < MLP_ROWS; rp += 2) {
            int r = rp + half;
            float acc2 = fc2b[j];
#pragma unroll
            for (int o = 0; o < 64; ++o)
                acc2 = fmaf(a1l[wid][r][o], fc2w[o * 32 + j], acc2);
            float p = fmaxf(acc2, 0.f) * outw[j];
            for (int m = 16; m; m >>= 1) p += __shfl_xor(p, m, 32);
            if (j == 0) {
                int row = base + r;
                if (row < bsize) out[row] = 1.f / (1.f + expf(-(p + ob)));
            }
        }
    }
}

extern "C" void kernel_launch(void* const* d_in, const int* in_sizes, int n_in,
                              void* d_out, int out_size, void* d_ws, size_t ws_size,
                              hipStream_t stream) {
    const float* x = (const float*)d_in[0];
    const float* W1 = (const float*)d_in[1];
    const float* b1 = (const float*)d_in[2];
    const float* W2 = (const float*)d_in[3];
    const float* b2 = (const float*)d_in[4];
    const float* fc1w = (const float*)d_in[5];
    const float* fc1b = (const float*)d_in[6];
    const float* fc2w = (const float*)d_in[7];
    const float* fc2b = (const float*)d_in[8];
    const float* outw = (const float*)d_in[9];
    const float* outb = (const float*)d_in[10];
    const int* ei = (const int*)d_in[11];
    const int* users = (const int*)d_in[12];
    const int* items = (const int*)d_in[13];

    const int n = in_sizes[0] / 64;   // 200000
    const int e = in_sizes[11] / 2;   // 640000
    const int b = in_sizes[12];       // 65536

    const int* srcp = ei;
    const int* dstp = ei + e;

    // ---- workspace bump allocator (256B aligned) ----
    char* wp = (char*)d_ws;
    auto alloc = [&](size_t bytes) { char* r = wp; wp += (bytes + 255) & ~(size_t)255; return r; };
    float* dinv   = (float*)alloc((size_t)n * 4);
    int*   cnt    = (int*)alloc((size_t)n * 4);       // becomes cursor in-place
    int*   off    = (int*)alloc((size_t)(n + 1) * 4);
    int*   bsums  = (int*)alloc(1024);
    int*   csrs   = (int*)alloc((size_t)e * 4);
    float* csrw   = (float*)alloc((size_t)e * 4);
    int*   flags  = (int*)alloc(2048 * 4);
    int*   numUsers = (int*)alloc(256);
    float* A1     = (float*)alloc((size_t)n * HDIM * 4);  // conv1 activation
    float* P1     = (float*)alloc((size_t)n * 64 * 4);    // conv1 pre-agg
    (void)alloc((size_t)n * 64 * 4);                      // pad so P2 fits at P1
    float* P2     = P1;                                   // conv2 pre-agg / A2 (in-place)

    const int nb_n = (n + 255) / 256;
    const int nb_scan = (n + 1023) / 1024;
    const int nb_rows = (n + 31) / 32;       // 6250
    const int nb_gather = (n + 3) / 4;       // 50000

    hipLaunchKernelGGL(init_kernel, dim3(nb_n), dim3(256), 0, stream, cnt, flags, off, n, e);
    hipLaunchKernelGGL(hist_kernel, dim3(2500), dim3(256), 0, stream, dstp, cnt, e);
    hipLaunchKernelGGL(dinv_kernel, dim3(nb_n), dim3(256), 0, stream, cnt, dinv, n);
    hipLaunchKernelGGL(scan_blocksums, dim3(nb_scan), dim3(256), 0, stream, cnt, bsums, n);
    hipLaunchKernelGGL(scan_top, dim3(1), dim3(256), 0, stream, bsums, nb_scan);
    hipLaunchKernelGGL(scan_final, dim3(nb_scan), dim3(256), 0, stream, cnt, bsums, off, cnt, n);
    hipLaunchKernelGGL(build_csr, dim3(2500), dim3(256), 0, stream,
                       srcp, dstp, dinv, cnt, csrs, csrw, e);

    // conv1: P1 = Agg(x) ; A1 = relu(P1@W1 + b1)
    hipLaunchKernelGGL((gather_pre<64>), dim3(nb_gather), dim3(256), 0, stream,
                       off, csrs, csrw, dinv, x, P1, n);
    hipLaunchKernelGGL((gcn_gemm<64, true>), dim3(nb_rows), dim3(256), 0, stream,
                       P1, W1, b1, A1, n);

    // conv2: P2 = Agg(A1) ; A2 = P2@W2 + b2 (in-place on P2)
    hipLaunchKernelGGL((gather_pre<128>), dim3(nb_gather), dim3(256), 0, stream,
                       off, csrs, csrw, dinv, A1, P2, n);
    hipLaunchKernelGGL((gcn_gemm<128, false>), dim3(nb_rows), dim3(256), 0, stream,
                       P2, W2, b2, P2, n);

    // num_users = n - |unique(items)|
    hipLaunchKernelGGL(mark_kernel, dim3((b + 255) / 256), dim3(256), 0, stream, items, flags, b);
    hipLaunchKernelGGL(count_kernel, dim3(1), dim3(256), 0, stream, flags, numUsers, n);

    hipLaunchKernelGGL(mlp_kernel, dim3(2048), dim3(256), 0, stream,
                       P2, users, items, numUsers, fc1w, fc1b, fc2w, fc2b,
                       outw, outb, (float*)d_out, b);
}

// Round 8
// 482.574 us; speedup vs baseline: 1.3617x; 1.3617x over previous
//
#include <hip/hip_runtime.h>
#include <math.h>

// ---------------------------------------------------------------------------
// TemporalGNN round 8 == round 5 resubmit (rounds 5-7 all died to
// GPUAcquisitionTimeout infra failures; source still unbenched; audited
// twice for OOB/aliasing/barrier hazards — none found).
//  - GEMM rewritten: 128x128 block tile, 8x8 per-thread register tile
//    (4 FMA per LDS float read -> balances LDS BW vs VALU), X staged
//    TRANSPOSED in 32-col chunks (xt[k][row]: broadcast conflict-free
//    reads), 32KB LDS, __launch_bounds__(256,3) -> ~4 blocks/CU.
//    Round-4 80KB-LDS GEMM was occupancy-killed (21%, 167us).
//  - conv2 restricted to used nodes (unique users + items ~57k of 200k):
//    mark -> scan -> compact list; gather2 + scatter-GEMM2 on <=67584 rows.
// ws: dinv|cnt|off|bsums|bsums2|csr_src|csr_w|flags|numUsers|mCnt|used|list|
//     bufA(A1: n*128)|bufB(P1 first half, later h_full: n*128)|P2c(67584*128)
// ---------------------------------------------------------------------------

#define HDIM 128
#define MAXM 67584   // 65536 users + 2048 items upper bound

__global__ __launch_bounds__(256) void init_kernel(int* __restrict__ cnt,
                                                   int* __restrict__ flags,
                                                   int* __restrict__ used,
                                                   int* __restrict__ off, int n, int e) {
    int i = blockIdx.x * 256 + threadIdx.x;
    if (i < n) { cnt[i] = 0; used[i] = 0; }
    if (i < 2048) flags[i] = 0;
    if (i == 0) off[n] = e;
}

__global__ __launch_bounds__(256) void hist_kernel(const int* __restrict__ dst,
                                                   int* __restrict__ cnt, int e) {
    int i = blockIdx.x * 256 + threadIdx.x;
    int stride = gridDim.x * 256;
    for (; i < e; i += stride) atomicAdd(&cnt[dst[i]], 1);
}

__global__ __launch_bounds__(256) void dinv_kernel(const int* __restrict__ cnt,
                                                   float* __restrict__ dinv, int n) {
    int i = blockIdx.x * 256 + threadIdx.x;
    if (i < n) dinv[i] = rsqrtf((float)cnt[i] + 1.0f);  // +1 = self-loop
}

// ---- generic 1024-per-block scan helpers ----
__global__ __launch_bounds__(256) void scan_blocksums(const int* __restrict__ v,
                                                      int* __restrict__ bsums, int n) {
    int base = blockIdx.x * 1024, t = threadIdx.x;
    int s = 0;
#pragma unroll
    for (int j = 0; j < 4; ++j) { int i = base + t * 4 + j; if (i < n) s += v[i]; }
    __shared__ int red[256];
    red[t] = s; __syncthreads();
    for (int o = 128; o; o >>= 1) { if (t < o) red[t] += red[t + o]; __syncthreads(); }
    if (t == 0) bsums[blockIdx.x] = red[0];
}

__global__ __launch_bounds__(256) void scan_top(int* __restrict__ bsums, int nb,
                                                int* __restrict__ total) {
    __shared__ int sh[256];
    int t = threadIdx.x;
    int v = (t < nb) ? bsums[t] : 0;
    sh[t] = v; __syncthreads();
    for (int o = 1; o < 256; o <<= 1) {
        int u = (t >= o) ? sh[t - o] : 0;
        __syncthreads();
        sh[t] += u;
        __syncthreads();
    }
    if (t < nb) bsums[t] = sh[t] - v;  // exclusive
    if (total && t == nb - 1) *total = sh[t];
}

__global__ __launch_bounds__(256) void scan_final(const int* __restrict__ cnt,
                                                  const int* __restrict__ bsums,
                                                  int* __restrict__ off,
                                                  int* cursor, int n) {
    int base = blockIdx.x * 1024, t = threadIdx.x;
    int v[4]; int s = 0;
#pragma unroll
    for (int j = 0; j < 4; ++j) { int i = base + t * 4 + j; v[j] = (i < n) ? cnt[i] : 0; s += v[j]; }
    __shared__ int sh[256];
    sh[t] = s; __syncthreads();
    for (int o = 1; o < 256; o <<= 1) {
        int u = (t >= o) ? sh[t - o] : 0;
        __syncthreads();
        sh[t] += u;
        __syncthreads();
    }
    int p = bsums[blockIdx.x] + (sh[t] - s);
#pragma unroll
    for (int j = 0; j < 4; ++j) {
        int i = base + t * 4 + j;
        if (i < n) { off[i] = p; cursor[i] = p; p += v[j]; }
    }
}

// compact: list[prefix(used)[i]] = i for used[i]!=0
__global__ __launch_bounds__(256) void compact_emit(const int* __restrict__ used,
                                                    const int* __restrict__ bsums,
                                                    int* __restrict__ list, int n) {
    int base = blockIdx.x * 1024, t = threadIdx.x;
    int v[4]; int s = 0;
#pragma unroll
    for (int j = 0; j < 4; ++j) { int i = base + t * 4 + j; v[j] = (i < n) ? used[i] : 0; s += v[j]; }
    __shared__ int sh[256];
    sh[t] = s; __syncthreads();
    for (int o = 1; o < 256; o <<= 1) {
        int u = (t >= o) ? sh[t - o] : 0;
        __syncthreads();
        sh[t] += u;
        __syncthreads();
    }
    int p = bsums[blockIdx.x] + (sh[t] - s);
#pragma unroll
    for (int j = 0; j < 4; ++j) {
        int i = base + t * 4 + j;
        if (i < n && v[j]) { list[p] = i; }
        p += v[j];
    }
}

__global__ __launch_bounds__(256) void build_csr(const int* __restrict__ src,
                                                 const int* __restrict__ dst,
                                                 const float* __restrict__ dinv,
                                                 int* __restrict__ cursor,
                                                 int* __restrict__ csr_src,
                                                 float* __restrict__ csr_w, int e) {
    int i = blockIdx.x * 256 + threadIdx.x;
    int stride = gridDim.x * 256;
    for (; i < e; i += stride) {
        int s = src[i], d = dst[i];
        int p = atomicAdd(&cursor[d], 1);
        csr_src[p] = s;
        csr_w[p] = dinv[s] * dinv[d];
    }
}

// ---- conv1 pre-aggregation over ALL nodes (D=64 input) ----
__global__ __launch_bounds__(256) void gather_pre64(const int* __restrict__ off,
                                                    const int* __restrict__ csr_src,
                                                    const float* __restrict__ csr_w,
                                                    const float* __restrict__ dinv,
                                                    const float* __restrict__ X,
                                                    float* __restrict__ P, int n) {
    const int lane = threadIdx.x & 63;
    const int d = blockIdx.x * 4 + (threadIdx.x >> 6);
    if (d >= n) return;
    const float di = dinv[d];
    const float sl = di * di;
    const int p0 = off[d], p1 = off[d + 1];
    float a = X[(size_t)d * 64 + lane] * sl;
    for (int p = p0; p < p1; ++p) {
        int s = csr_src[p];
        float w = csr_w[p];
        a = fmaf(X[(size_t)s * 64 + lane], w, a);
    }
    P[(size_t)d * 64 + lane] = a;
}

// ---- conv2 pre-aggregation over USED nodes only (D=128), compacted output ----
__global__ __launch_bounds__(256) void gather_pre128_list(const int* __restrict__ off,
                                                          const int* __restrict__ csr_src,
                                                          const float* __restrict__ csr_w,
                                                          const float* __restrict__ dinv,
                                                          const float* __restrict__ X,
                                                          const int* __restrict__ list,
                                                          const int* __restrict__ mPtr,
                                                          float* __restrict__ Pc) {
    const int lane = threadIdx.x & 63;
    const int i = blockIdx.x * 4 + (threadIdx.x >> 6);
    if (i >= *mPtr) return;
    const int d = list[i];
    const float di = dinv[d];
    const float sl = di * di;
    const int p0 = off[d], p1 = off[d + 1];
    const float2* X2 = (const float2*)X;
    float2 a = X2[(size_t)d * 64 + lane];
    a.x *= sl; a.y *= sl;
    for (int p = p0; p < p1; ++p) {
        int s = csr_src[p];
        float w = csr_w[p];
        float2 v = X2[(size_t)s * 64 + lane];
        a.x = fmaf(v.x, w, a.x);
        a.y = fmaf(v.y, w, a.y);
    }
    ((float2*)Pc)[(size_t)i * 64 + lane] = a;
}

// ---- register-blocked GEMM: out = X @ W + bias ----
// Block: 128 rows x 128 cols; thread (tyg,tx) = 8x8 register tile.
// X staged TRANSPOSED per 32-col chunk: xt[k][row] -> 4-addr broadcast reads.
// SCATTER: X is compacted [m][K], output row = rowlist[r].
template <int K, bool RELU, bool SCATTER>
__global__ __launch_bounds__(256, 3) void gemm_tile(const float* __restrict__ X,
                                                    const float* __restrict__ W,
                                                    const float* __restrict__ bias,
                                                    float* __restrict__ out,
                                                    const int* __restrict__ rowlist,
                                                    const int* __restrict__ mPtr,
                                                    int n) {
    __shared__ float xt[32][128];   // 16 KB, transposed X chunk
    __shared__ float wl[32][128];   // 16 KB, W chunk

    const int m = SCATTER ? *mPtr : n;
    const int rowBase = blockIdx.x * 128;
    if (rowBase >= m) return;

    const int tid = threadIdx.x;
    const int tx = tid & 15;        // col group (8 cols)
    const int tyg = tid >> 4;       // row group (8 rows)

    const int srow = tid >> 1;            // staging: row 0..127
    const int scol = (tid & 1) * 16;      // staging: col half
    const int grow = rowBase + srow;
    const bool valid = grow < m;

    float acc[8][8] = {};

    for (int chunk = 0; chunk < K / 32; ++chunk) {
        __syncthreads();   // previous chunk's compute done
        // X chunk -> transposed LDS (2-way write aliasing only)
#pragma unroll
        for (int q = 0; q < 4; ++q) {
            int c = scol + q * 4;
            float4 v = {0.f, 0.f, 0.f, 0.f};
            if (valid) v = *(const float4*)&X[(size_t)grow * K + chunk * 32 + c];
            xt[c + 0][srow] = v.x;
            xt[c + 1][srow] = v.y;
            xt[c + 2][srow] = v.z;
            xt[c + 3][srow] = v.w;
        }
        // W chunk -> LDS linear
        {
            const float4* Ws = (const float4*)(W + (size_t)chunk * 32 * 128);
            float4* wl4 = (float4*)wl;
#pragma unroll
            for (int q = 0; q < 4; ++q) wl4[tid + q * 256] = Ws[tid + q * 256];
        }
        __syncthreads();

#pragma unroll 2
        for (int k = 0; k < 32; ++k) {
            float4 xa = *(const float4*)&xt[k][tyg * 8];
            float4 xb = *(const float4*)&xt[k][tyg * 8 + 4];
            float4 wa = *(const float4*)&wl[k][tx * 8];
            float4 wb = *(const float4*)&wl[k][tx * 8 + 4];
            float xv[8] = {xa.x, xa.y, xa.z, xa.w, xb.x, xb.y, xb.z, xb.w};
            float wv[8] = {wa.x, wa.y, wa.z, wa.w, wb.x, wb.y, wb.z, wb.w};
#pragma unroll
            for (int i = 0; i < 8; ++i)
#pragma unroll
                for (int j = 0; j < 8; ++j)
                    acc[i][j] = fmaf(xv[i], wv[j], acc[i][j]);
        }
    }

    float4 bv0 = *(const float4*)&bias[tx * 8];
    float4 bv1 = *(const float4*)&bias[tx * 8 + 4];
    float bv[8] = {bv0.x, bv0.y, bv0.z, bv0.w, bv1.x, bv1.y, bv1.z, bv1.w};

#pragma unroll
    for (int i = 0; i < 8; ++i) {
        int r = rowBase + tyg * 8 + i;
        if (r < m) {
            float o[8];
#pragma unroll
            for (int j = 0; j < 8; ++j) {
                o[j] = acc[i][j] + bv[j];
                if (RELU) o[j] = fmaxf(o[j], 0.f);
            }
            int orow = SCATTER ? rowlist[r] : r;
            float* op = out + (size_t)orow * HDIM + tx * 8;
            *(float4*)op = {o[0], o[1], o[2], o[3]};
            *(float4*)(op + 4) = {o[4], o[5], o[6], o[7]};
        }
    }
}

__global__ __launch_bounds__(256) void mark_kernel(const int* __restrict__ items,
                                                   int* __restrict__ flags, int b) {
    int i = blockIdx.x * 256 + threadIdx.x;
    if (i < b) flags[items[i]] = 1;
}

__global__ __launch_bounds__(256) void count_kernel(const int* __restrict__ flags,
                                                    int* __restrict__ numUsers, int n) {
    __shared__ int sred[4];
    int tid = threadIdx.x;
    int s = 0;
    for (int i = tid; i < 2048; i += 256) s += flags[i];
    for (int m = 32; m; m >>= 1) s += __shfl_xor(s, m, 64);
    if ((tid & 63) == 0) sred[tid >> 6] = s;
    __syncthreads();
    if (tid == 0) *numUsers = n - (sred[0] + sred[1] + sred[2] + sred[3]);
}

__global__ __launch_bounds__(256) void mark_used(const int* __restrict__ users,
                                                 const int* __restrict__ items,
                                                 const int* __restrict__ nuPtr,
                                                 int* __restrict__ used, int b, int n) {
    int i = blockIdx.x * 256 + threadIdx.x;
    if (i < b) {
        used[users[i]] = 1;
        int idx = *nuPtr + items[i];
        if (idx < n) used[idx] = 1;
    }
}

#define MLP_ROWS 8
__global__ __launch_bounds__(256) void mlp_kernel(
    const float* __restrict__ h, const int* __restrict__ users,
    const int* __restrict__ items, const int* __restrict__ numUsersPtr,
    const float* __restrict__ fc1w, const float* __restrict__ fc1b,
    const float* __restrict__ fc2w, const float* __restrict__ fc2b,
    const float* __restrict__ outw, const float* __restrict__ outb,
    float* __restrict__ out, int bsize) {
    __shared__ float zl[4][MLP_ROWS][256];
    __shared__ float a1l[4][MLP_ROWS][64];

    const int tid = threadIdx.x;
    const int lane = tid & 63;
    const int wid = tid >> 6;
    const int nu = *numUsersPtr;
    const int wavesTotal = (gridDim.x * 256) >> 6;
    const int gw = (blockIdx.x * 256 + tid) >> 6;
    const float f1b = fc1b[lane];
    const float ob = outb[0];
    const float2* h2 = (const float2*)h;

    for (int base = gw * MLP_ROWS; base < bsize; base += wavesTotal * MLP_ROWS) {
#pragma unroll
        for (int r = 0; r < MLP_ROWS; ++r) {
            int row = base + r;
            if (row < bsize) {
                int u = users[row];
                int it = nu + items[row];
                float2 uv = h2[(size_t)u * 64 + lane];
                float2 iv = h2[(size_t)it * 64 + lane];
                *(float2*)&zl[wid][r][2 * lane] = uv;
                *(float2*)&zl[wid][r][128 + 2 * lane] = iv;
            }
        }
        float acc[MLP_ROWS];
#pragma unroll
        for (int r = 0; r < MLP_ROWS; ++r) acc[r] = f1b;
        for (int k = 0; k < 256; k += 4) {
            float w0 = fc1w[k * 64 + lane];
            float w1 = fc1w[(k + 1) * 64 + lane];
            float w2 = fc1w[(k + 2) * 64 + lane];
            float w3 = fc1w[(k + 3) * 64 + lane];
#pragma unroll
            for (int r = 0; r < MLP_ROWS; ++r) {
                const float4 z4 = *(const float4*)&zl[wid][r][k];
                acc[r] = fmaf(z4.x, w0, acc[r]);
                acc[r] = fmaf(z4.y, w1, acc[r]);
                acc[r] = fmaf(z4.z, w2, acc[r]);
                acc[r] = fmaf(z4.w, w3, acc[r]);
            }
        }
#pragma unroll
        for (int r = 0; r < MLP_ROWS; ++r) a1l[wid][r][lane] = fmaxf(acc[r], 0.f);

        const int half = lane >> 5, j = lane & 31;
        for (int rp = 0; rp < MLP_ROWS; rp += 2) {
            int r = rp + half;
            float acc2 = fc2b[j];
#pragma unroll
            for (int o = 0; o < 64; ++o)
                acc2 = fmaf(a1l[wid][r][o], fc2w[o * 32 + j], acc2);
            float p = fmaxf(acc2, 0.f) * outw[j];
            for (int mm = 16; mm; mm >>= 1) p += __shfl_xor(p, mm, 32);
            if (j == 0) {
                int row = base + r;
                if (row < bsize) out[row] = 1.f / (1.f + expf(-(p + ob)));
            }
        }
    }
}

extern "C" void kernel_launch(void* const* d_in, const int* in_sizes, int n_in,
                              void* d_out, int out_size, void* d_ws, size_t ws_size,
                              hipStream_t stream) {
    const float* x = (const float*)d_in[0];
    const float* W1 = (const float*)d_in[1];
    const float* b1 = (const float*)d_in[2];
    const float* W2 = (const float*)d_in[3];
    const float* b2 = (const float*)d_in[4];
    const float* fc1w = (const float*)d_in[5];
    const float* fc1b = (const float*)d_in[6];
    const float* fc2w = (const float*)d_in[7];
    const float* fc2b = (const float*)d_in[8];
    const float* outw = (const float*)d_in[9];
    const float* outb = (const float*)d_in[10];
    const int* ei = (const int*)d_in[11];
    const int* users = (const int*)d_in[12];
    const int* items = (const int*)d_in[13];

    const int n = in_sizes[0] / 64;   // 200000
    const int e = in_sizes[11] / 2;   // 640000
    const int b = in_sizes[12];       // 65536

    const int* srcp = ei;
    const int* dstp = ei + e;

    // ---- workspace bump allocator (256B aligned) ----
    char* wp = (char*)d_ws;
    auto alloc = [&](size_t bytes) { char* r = wp; wp += (bytes + 255) & ~(size_t)255; return r; };
    float* dinv   = (float*)alloc((size_t)n * 4);
    int*   cnt    = (int*)alloc((size_t)n * 4);       // becomes CSR cursor in-place
    int*   off    = (int*)alloc((size_t)(n + 1) * 4);
    int*   bsums  = (int*)alloc(1024);
    int*   bsums2 = (int*)alloc(1024);
    int*   csrs   = (int*)alloc((size_t)e * 4);
    float* csrw   = (float*)alloc((size_t)e * 4);
    int*   flags  = (int*)alloc(2048 * 4);
    int*   numUsers = (int*)alloc(256);
    int*   mCnt   = (int*)alloc(256);
    int*   used   = (int*)alloc((size_t)n * 4);
    int*   list   = (int*)alloc((size_t)MAXM * 4);
    float* bufA   = (float*)alloc((size_t)n * HDIM * 4);   // A1
    float* bufB   = (float*)alloc((size_t)n * HDIM * 4);   // P1 (first half), then h_full
    float* P2c    = (float*)alloc((size_t)MAXM * HDIM * 4);
    float* P1     = bufB;   // n*64 floats = first half of bufB

    const int nb_n = (n + 255) / 256;
    const int nb_scan = (n + 1023) / 1024;       // 196
    const int nb_g1 = (n + 3) / 4;               // 50000
    const int nb_g2 = (MAXM + 3) / 4;            // 16896
    const int nb_gemm1 = (n + 127) / 128;        // 1563
    const int nb_gemm2 = (MAXM + 127) / 128;     // 528

    // degree + CSR build
    hipLaunchKernelGGL(init_kernel, dim3(nb_n), dim3(256), 0, stream, cnt, flags, used, off, n, e);
    hipLaunchKernelGGL(hist_kernel, dim3(2500), dim3(256), 0, stream, dstp, cnt, e);
    hipLaunchKernelGGL(dinv_kernel, dim3(nb_n), dim3(256), 0, stream, cnt, dinv, n);
    hipLaunchKernelGGL(scan_blocksums, dim3(nb_scan), dim3(256), 0, stream, cnt, bsums, n);
    hipLaunchKernelGGL(scan_top, dim3(1), dim3(256), 0, stream, bsums, nb_scan, (int*)nullptr);
    hipLaunchKernelGGL(scan_final, dim3(nb_scan), dim3(256), 0, stream, cnt, bsums, off, cnt, n);
    hipLaunchKernelGGL(build_csr, dim3(2500), dim3(256), 0, stream,
                       srcp, dstp, dinv, cnt, csrs, csrw, e);

    // num_users + used-node compaction
    hipLaunchKernelGGL(mark_kernel, dim3((b + 255) / 256), dim3(256), 0, stream, items, flags, b);
    hipLaunchKernelGGL(count_kernel, dim3(1), dim3(256), 0, stream, flags, numUsers, n);
    hipLaunchKernelGGL(mark_used, dim3((b + 255) / 256), dim3(256), 0, stream,
                       users, items, numUsers, used, b, n);
    hipLaunchKernelGGL(scan_blocksums, dim3(nb_scan), dim3(256), 0, stream, used, bsums2, n);
    hipLaunchKernelGGL(scan_top, dim3(1), dim3(256), 0, stream, bsums2, nb_scan, mCnt);
    hipLaunchKernelGGL(compact_emit, dim3(nb_scan), dim3(256), 0, stream, used, bsums2, list, n);

    // conv1 (all nodes): P1 = Agg(x); A1 = relu(P1@W1 + b1)
    hipLaunchKernelGGL(gather_pre64, dim3(nb_g1), dim3(256), 0, stream,
                       off, csrs, csrw, dinv, x, P1, n);
    hipLaunchKernelGGL((gemm_tile<64, true, false>), dim3(nb_gemm1), dim3(256), 0, stream,
                       P1, W1, b1, bufA, (const int*)nullptr, (const int*)nullptr, n);

    // conv2 (used nodes only): P2c[i] = Agg(A1, list[i]); h[list[i]] = P2c[i]@W2 + b2
    hipLaunchKernelGGL(gather_pre128_list, dim3(nb_g2), dim3(256), 0, stream,
                       off, csrs, csrw, dinv, bufA, list, mCnt, P2c);
    hipLaunchKernelGGL((gemm_tile<128, false, true>), dim3(nb_gemm2), dim3(256), 0, stream,
                       P2c, W2, b2, bufB, list, mCnt, n);

    // gather + MLP + sigmoid
    hipLaunchKernelGGL(mlp_kernel, dim3(2048), dim3(256), 0, stream,
                       bufB, users, items, numUsers, fc1w, fc1b, fc2w, fc2b,
                       outw, outb, (float*)d_out, b);
}

// Round 12
// 459.087 us; speedup vs baseline: 1.4314x; 1.0512x over previous
//
#include <hip/hip_runtime.h>
#include <math.h>

// ---------------------------------------------------------------------------
// TemporalGNN round 12 == round 9 resubmit (rounds 9-11 all died to
// GPUAcquisitionTimeout infra failures; source unbenched).
// Round-8 profile: gather_pre64 = 103us top dispatch, latency-bound
// (VALUBusy 14%, HBM 20%, occ 69%) — serial dependent edge loop = 1
// outstanding row-load per wave. Fix: batch the edge loop 4-wide
// (4 independent X-row loads in flight per iteration) in BOTH gathers.
// Everything else unchanged from round 8 (482us measured).
// ws: dinv|cnt|off|bsums|bsums2|csr_src|csr_w|flags|numUsers|mCnt|used|list|
//     bufA(A1: n*128)|bufB(P1 first half, later h_full: n*128)|P2c(67584*128)
// ---------------------------------------------------------------------------

#define HDIM 128
#define MAXM 67584   // 65536 users + 2048 items upper bound

__global__ __launch_bounds__(256) void init_kernel(int* __restrict__ cnt,
                                                   int* __restrict__ flags,
                                                   int* __restrict__ used,
                                                   int* __restrict__ off, int n, int e) {
    int i = blockIdx.x * 256 + threadIdx.x;
    if (i < n) { cnt[i] = 0; used[i] = 0; }
    if (i < 2048) flags[i] = 0;
    if (i == 0) off[n] = e;
}

__global__ __launch_bounds__(256) void hist_kernel(const int* __restrict__ dst,
                                                   int* __restrict__ cnt, int e) {
    int i = blockIdx.x * 256 + threadIdx.x;
    int stride = gridDim.x * 256;
    for (; i < e; i += stride) atomicAdd(&cnt[dst[i]], 1);
}

__global__ __launch_bounds__(256) void dinv_kernel(const int* __restrict__ cnt,
                                                   float* __restrict__ dinv, int n) {
    int i = blockIdx.x * 256 + threadIdx.x;
    if (i < n) dinv[i] = rsqrtf((float)cnt[i] + 1.0f);  // +1 = self-loop
}

// ---- generic 1024-per-block scan helpers ----
__global__ __launch_bounds__(256) void scan_blocksums(const int* __restrict__ v,
                                                      int* __restrict__ bsums, int n) {
    int base = blockIdx.x * 1024, t = threadIdx.x;
    int s = 0;
#pragma unroll
    for (int j = 0; j < 4; ++j) { int i = base + t * 4 + j; if (i < n) s += v[i]; }
    __shared__ int red[256];
    red[t] = s; __syncthreads();
    for (int o = 128; o; o >>= 1) { if (t < o) red[t] += red[t + o]; __syncthreads(); }
    if (t == 0) bsums[blockIdx.x] = red[0];
}

__global__ __launch_bounds__(256) void scan_top(int* __restrict__ bsums, int nb,
                                                int* __restrict__ total) {
    __shared__ int sh[256];
    int t = threadIdx.x;
    int v = (t < nb) ? bsums[t] : 0;
    sh[t] = v; __syncthreads();
    for (int o = 1; o < 256; o <<= 1) {
        int u = (t >= o) ? sh[t - o] : 0;
        __syncthreads();
        sh[t] += u;
        __syncthreads();
    }
    if (t < nb) bsums[t] = sh[t] - v;  // exclusive
    if (total && t == nb - 1) *total = sh[t];
}

__global__ __launch_bounds__(256) void scan_final(const int* __restrict__ cnt,
                                                  const int* __restrict__ bsums,
                                                  int* __restrict__ off,
                                                  int* cursor, int n) {
    int base = blockIdx.x * 1024, t = threadIdx.x;
    int v[4]; int s = 0;
#pragma unroll
    for (int j = 0; j < 4; ++j) { int i = base + t * 4 + j; v[j] = (i < n) ? cnt[i] : 0; s += v[j]; }
    __shared__ int sh[256];
    sh[t] = s; __syncthreads();
    for (int o = 1; o < 256; o <<= 1) {
        int u = (t >= o) ? sh[t - o] : 0;
        __syncthreads();
        sh[t] += u;
        __syncthreads();
    }
    int p = bsums[blockIdx.x] + (sh[t] - s);
#pragma unroll
    for (int j = 0; j < 4; ++j) {
        int i = base + t * 4 + j;
        if (i < n) { off[i] = p; cursor[i] = p; p += v[j]; }
    }
}

// compact: list[prefix(used)[i]] = i for used[i]!=0
__global__ __launch_bounds__(256) void compact_emit(const int* __restrict__ used,
                                                    const int* __restrict__ bsums,
                                                    int* __restrict__ list, int n) {
    int base = blockIdx.x * 1024, t = threadIdx.x;
    int v[4]; int s = 0;
#pragma unroll
    for (int j = 0; j < 4; ++j) { int i = base + t * 4 + j; v[j] = (i < n) ? used[i] : 0; s += v[j]; }
    __shared__ int sh[256];
    sh[t] = s; __syncthreads();
    for (int o = 1; o < 256; o <<= 1) {
        int u = (t >= o) ? sh[t - o] : 0;
        __syncthreads();
        sh[t] += u;
        __syncthreads();
    }
    int p = bsums[blockIdx.x] + (sh[t] - s);
#pragma unroll
    for (int j = 0; j < 4; ++j) {
        int i = base + t * 4 + j;
        if (i < n && v[j]) { list[p] = i; }
        p += v[j];
    }
}

__global__ __launch_bounds__(256) void build_csr(const int* __restrict__ src,
                                                 const int* __restrict__ dst,
                                                 const float* __restrict__ dinv,
                                                 int* __restrict__ cursor,
                                                 int* __restrict__ csr_src,
                                                 float* __restrict__ csr_w, int e) {
    int i = blockIdx.x * 256 + threadIdx.x;
    int stride = gridDim.x * 256;
    for (; i < e; i += stride) {
        int s = src[i], d = dst[i];
        int p = atomicAdd(&cursor[d], 1);
        csr_src[p] = s;
        csr_w[p] = dinv[s] * dinv[d];
    }
}

// ---- conv1 pre-aggregation over ALL nodes (D=64 input) ----
// Edge loop batched 4-wide: 4 independent row loads in flight per iter
// (round-8 profile: serial loop was latency-bound, VALUBusy 14%).
__global__ __launch_bounds__(256) void gather_pre64(const int* __restrict__ off,
                                                    const int* __restrict__ csr_src,
                                                    const float* __restrict__ csr_w,
                                                    const float* __restrict__ dinv,
                                                    const float* __restrict__ X,
                                                    float* __restrict__ P, int n) {
    const int lane = threadIdx.x & 63;
    const int d = blockIdx.x * 4 + (threadIdx.x >> 6);
    if (d >= n) return;
    const float di = dinv[d];
    const float sl = di * di;
    const int p0 = off[d], p1 = off[d + 1];

    float a = X[(size_t)d * 64 + lane] * sl;

    int p = p0;
    for (; p + 4 <= p1; p += 4) {
        int s0 = csr_src[p + 0], s1 = csr_src[p + 1];
        int s2 = csr_src[p + 2], s3 = csr_src[p + 3];
        float w0 = csr_w[p + 0], w1 = csr_w[p + 1];
        float w2 = csr_w[p + 2], w3 = csr_w[p + 3];
        float v0 = X[(size_t)s0 * 64 + lane];
        float v1 = X[(size_t)s1 * 64 + lane];
        float v2 = X[(size_t)s2 * 64 + lane];
        float v3 = X[(size_t)s3 * 64 + lane];
        a = fmaf(v0, w0, a);
        a = fmaf(v1, w1, a);
        a = fmaf(v2, w2, a);
        a = fmaf(v3, w3, a);
    }
    if (p + 2 <= p1) {
        int s0 = csr_src[p + 0], s1 = csr_src[p + 1];
        float w0 = csr_w[p + 0], w1 = csr_w[p + 1];
        float v0 = X[(size_t)s0 * 64 + lane];
        float v1 = X[(size_t)s1 * 64 + lane];
        a = fmaf(v0, w0, a);
        a = fmaf(v1, w1, a);
        p += 2;
    }
    if (p < p1) {
        a = fmaf(X[(size_t)csr_src[p] * 64 + lane], csr_w[p], a);
    }
    P[(size_t)d * 64 + lane] = a;
}

// ---- conv2 pre-aggregation over USED nodes only (D=128), compacted output ----
// Same 4-wide edge batching; lanes hold float2 (512B rows).
__global__ __launch_bounds__(256) void gather_pre128_list(const int* __restrict__ off,
                                                          const int* __restrict__ csr_src,
                                                          const float* __restrict__ csr_w,
                                                          const float* __restrict__ dinv,
                                                          const float* __restrict__ X,
                                                          const int* __restrict__ list,
                                                          const int* __restrict__ mPtr,
                                                          float* __restrict__ Pc) {
    const int lane = threadIdx.x & 63;
    const int i = blockIdx.x * 4 + (threadIdx.x >> 6);
    if (i >= *mPtr) return;
    const int d = list[i];
    const float di = dinv[d];
    const float sl = di * di;
    const int p0 = off[d], p1 = off[d + 1];
    const float2* X2 = (const float2*)X;

    float2 a = X2[(size_t)d * 64 + lane];
    a.x *= sl; a.y *= sl;

    int p = p0;
    for (; p + 4 <= p1; p += 4) {
        int s0 = csr_src[p + 0], s1 = csr_src[p + 1];
        int s2 = csr_src[p + 2], s3 = csr_src[p + 3];
        float w0 = csr_w[p + 0], w1 = csr_w[p + 1];
        float w2 = csr_w[p + 2], w3 = csr_w[p + 3];
        float2 v0 = X2[(size_t)s0 * 64 + lane];
        float2 v1 = X2[(size_t)s1 * 64 + lane];
        float2 v2 = X2[(size_t)s2 * 64 + lane];
        float2 v3 = X2[(size_t)s3 * 64 + lane];
        a.x = fmaf(v0.x, w0, a.x); a.y = fmaf(v0.y, w0, a.y);
        a.x = fmaf(v1.x, w1, a.x); a.y = fmaf(v1.y, w1, a.y);
        a.x = fmaf(v2.x, w2, a.x); a.y = fmaf(v2.y, w2, a.y);
        a.x = fmaf(v3.x, w3, a.x); a.y = fmaf(v3.y, w3, a.y);
    }
    if (p + 2 <= p1) {
        int s0 = csr_src[p + 0], s1 = csr_src[p + 1];
        float w0 = csr_w[p + 0], w1 = csr_w[p + 1];
        float2 v0 = X2[(size_t)s0 * 64 + lane];
        float2 v1 = X2[(size_t)s1 * 64 + lane];
        a.x = fmaf(v0.x, w0, a.x); a.y = fmaf(v0.y, w0, a.y);
        a.x = fmaf(v1.x, w1, a.x); a.y = fmaf(v1.y, w1, a.y);
        p += 2;
    }
    if (p < p1) {
        float w = csr_w[p];
        float2 v = X2[(size_t)csr_src[p] * 64 + lane];
        a.x = fmaf(v.x, w, a.x); a.y = fmaf(v.y, w, a.y);
    }
    ((float2*)Pc)[(size_t)i * 64 + lane] = a;
}

// ---- register-blocked GEMM: out = X @ W + bias ----
// Block: 128 rows x 128 cols; thread (tyg,tx) = 8x8 register tile.
// X staged TRANSPOSED per 32-col chunk: xt[k][row] -> 4-addr broadcast reads.
// SCATTER: X is compacted [m][K], output row = rowlist[r].
template <int K, bool RELU, bool SCATTER>
__global__ __launch_bounds__(256, 3) void gemm_tile(const float* __restrict__ X,
                                                    const float* __restrict__ W,
                                                    const float* __restrict__ bias,
                                                    float* __restrict__ out,
                                                    const int* __restrict__ rowlist,
                                                    const int* __restrict__ mPtr,
                                                    int n) {
    __shared__ float xt[32][128];   // 16 KB, transposed X chunk
    __shared__ float wl[32][128];   // 16 KB, W chunk

    const int m = SCATTER ? *mPtr : n;
    const int rowBase = blockIdx.x * 128;
    if (rowBase >= m) return;

    const int tid = threadIdx.x;
    const int tx = tid & 15;        // col group (8 cols)
    const int tyg = tid >> 4;       // row group (8 rows)

    const int srow = tid >> 1;            // staging: row 0..127
    const int scol = (tid & 1) * 16;      // staging: col half
    const int grow = rowBase + srow;
    const bool valid = grow < m;

    float acc[8][8] = {};

    for (int chunk = 0; chunk < K / 32; ++chunk) {
        __syncthreads();   // previous chunk's compute done
        // X chunk -> transposed LDS (2-way write aliasing only)
#pragma unroll
        for (int q = 0; q < 4; ++q) {
            int c = scol + q * 4;
            float4 v = {0.f, 0.f, 0.f, 0.f};
            if (valid) v = *(const float4*)&X[(size_t)grow * K + chunk * 32 + c];
            xt[c + 0][srow] = v.x;
            xt[c + 1][srow] = v.y;
            xt[c + 2][srow] = v.z;
            xt[c + 3][srow] = v.w;
        }
        // W chunk -> LDS linear
        {
            const float4* Ws = (const float4*)(W + (size_t)chunk * 32 * 128);
            float4* wl4 = (float4*)wl;
#pragma unroll
            for (int q = 0; q < 4; ++q) wl4[tid + q * 256] = Ws[tid + q * 256];
        }
        __syncthreads();

#pragma unroll 2
        for (int k = 0; k < 32; ++k) {
            float4 xa = *(const float4*)&xt[k][tyg * 8];
            float4 xb = *(const float4*)&xt[k][tyg * 8 + 4];
            float4 wa = *(const float4*)&wl[k][tx * 8];
            float4 wb = *(const float4*)&wl[k][tx * 8 + 4];
            float xv[8] = {xa.x, xa.y, xa.z, xa.w, xb.x, xb.y, xb.z, xb.w};
            float wv[8] = {wa.x, wa.y, wa.z, wa.w, wb.x, wb.y, wb.z, wb.w};
#pragma unroll
            for (int i = 0; i < 8; ++i)
#pragma unroll
                for (int j = 0; j < 8; ++j)
                    acc[i][j] = fmaf(xv[i], wv[j], acc[i][j]);
        }
    }

    float4 bv0 = *(const float4*)&bias[tx * 8];
    float4 bv1 = *(const float4*)&bias[tx * 8 + 4];
    float bv[8] = {bv0.x, bv0.y, bv0.z, bv0.w, bv1.x, bv1.y, bv1.z, bv1.w};

#pragma unroll
    for (int i = 0; i < 8; ++i) {
        int r = rowBase + tyg * 8 + i;
        if (r < m) {
            float o[8];
#pragma unroll
            for (int j = 0; j < 8; ++j) {
                o[j] = acc[i][j] + bv[j];
                if (RELU) o[j] = fmaxf(o[j], 0.f);
            }
            int orow = SCATTER ? rowlist[r] : r;
            float* op = out + (size_t)orow * HDIM + tx * 8;
            *(float4*)op = {o[0], o[1], o[2], o[3]};
            *(float4*)(op + 4) = {o[4], o[5], o[6], o[7]};
        }
    }
}

__global__ __launch_bounds__(256) void mark_kernel(const int* __restrict__ items,
                                                   int* __restrict__ flags, int b) {
    int i = blockIdx.x * 256 + threadIdx.x;
    if (i < b) flags[items[i]] = 1;
}

__global__ __launch_bounds__(256) void count_kernel(const int* __restrict__ flags,
                                                    int* __restrict__ numUsers, int n) {
    __shared__ int sred[4];
    int tid = threadIdx.x;
    int s = 0;
    for (int i = tid; i < 2048; i += 256) s += flags[i];
    for (int m = 32; m; m >>= 1) s += __shfl_xor(s, m, 64);
    if ((tid & 63) == 0) sred[tid >> 6] = s;
    __syncthreads();
    if (tid == 0) *numUsers = n - (sred[0] + sred[1] + sred[2] + sred[3]);
}

__global__ __launch_bounds__(256) void mark_used(const int* __restrict__ users,
                                                 const int* __restrict__ items,
                                                 const int* __restrict__ nuPtr,
                                                 int* __restrict__ used, int b, int n) {
    int i = blockIdx.x * 256 + threadIdx.x;
    if (i < b) {
        used[users[i]] = 1;
        int idx = *nuPtr + items[i];
        if (idx < n) used[idx] = 1;
    }
}

#define MLP_ROWS 8
__global__ __launch_bounds__(256) void mlp_kernel(
    const float* __restrict__ h, const int* __restrict__ users,
    const int* __restrict__ items, const int* __restrict__ numUsersPtr,
    const float* __restrict__ fc1w, const float* __restrict__ fc1b,
    const float* __restrict__ fc2w, const float* __restrict__ fc2b,
    const float* __restrict__ outw, const float* __restrict__ outb,
    float* __restrict__ out, int bsize) {
    __shared__ float zl[4][MLP_ROWS][256];
    __shared__ float a1l[4][MLP_ROWS][64];

    const int tid = threadIdx.x;
    const int lane = tid & 63;
    const int wid = tid >> 6;
    const int nu = *numUsersPtr;
    const int wavesTotal = (gridDim.x * 256) >> 6;
    const int gw = (blockIdx.x * 256 + tid) >> 6;
    const float f1b = fc1b[lane];
    const float ob = outb[0];
    const float2* h2 = (const float2*)h;

    for (int base = gw * MLP_ROWS; base < bsize; base += wavesTotal * MLP_ROWS) {
#pragma unroll
        for (int r = 0; r < MLP_ROWS; ++r) {
            int row = base + r;
            if (row < bsize) {
                int u = users[row];
                int it = nu + items[row];
                float2 uv = h2[(size_t)u * 64 + lane];
                float2 iv = h2[(size_t)it * 64 + lane];
                *(float2*)&zl[wid][r][2 * lane] = uv;
                *(float2*)&zl[wid][r][128 + 2 * lane] = iv;
            }
        }
        float acc[MLP_ROWS];
#pragma unroll
        for (int r = 0; r < MLP_ROWS; ++r) acc[r] = f1b;
        for (int k = 0; k < 256; k += 4) {
            float w0 = fc1w[k * 64 + lane];
            float w1 = fc1w[(k + 1) * 64 + lane];
            float w2 = fc1w[(k + 2) * 64 + lane];
            float w3 = fc1w[(k + 3) * 64 + lane];
#pragma unroll
            for (int r = 0; r < MLP_ROWS; ++r) {
                const float4 z4 = *(const float4*)&zl[wid][r][k];
                acc[r] = fmaf(z4.x, w0, acc[r]);
                acc[r] = fmaf(z4.y, w1, acc[r]);
                acc[r] = fmaf(z4.z, w2, acc[r]);
                acc[r] = fmaf(z4.w, w3, acc[r]);
            }
        }
#pragma unroll
        for (int r = 0; r < MLP_ROWS; ++r) a1l[wid][r][lane] = fmaxf(acc[r], 0.f);

        const int half = lane >> 5, j = lane & 31;
        for (int rp = 0; rp < MLP_ROWS; rp += 2) {
            int r = rp + half;
            float acc2 = fc2b[j];
#pragma unroll
            for (int o = 0; o < 64; ++o)
                acc2 = fmaf(a1l[wid][r][o], fc2w[o * 32 + j], acc2);
            float p = fmaxf(acc2, 0.f) * outw[j];
            for (int mm = 16; mm; mm >>= 1) p += __shfl_xor(p, mm, 32);
            if (j == 0) {
                int row = base + r;
                if (row < bsize) out[row] = 1.f / (1.f + expf(-(p + ob)));
            }
        }
    }
}

extern "C" void kernel_launch(void* const* d_in, const int* in_sizes, int n_in,
                              void* d_out, int out_size, void* d_ws, size_t ws_size,
                              hipStream_t stream) {
    const float* x = (const float*)d_in[0];
    const float* W1 = (const float*)d_in[1];
    const float* b1 = (const float*)d_in[2];
    const float* W2 = (const float*)d_in[3];
    const float* b2 = (const float*)d_in[4];
    const float* fc1w = (const float*)d_in[5];
    const float* fc1b = (const float*)d_in[6];
    const float* fc2w = (const float*)d_in[7];
    const float* fc2b = (const float*)d_in[8];
    const float* outw = (const float*)d_in[9];
    const float* outb = (const float*)d_in[10];
    const int* ei = (const int*)d_in[11];
    const int* users = (const int*)d_in[12];
    const int* items = (const int*)d_in[13];

    const int n = in_sizes[0] / 64;   // 200000
    const int e = in_sizes[11] / 2;   // 640000
    const int b = in_sizes[12];       // 65536

    const int* srcp = ei;
    const int* dstp = ei + e;

    // ---- workspace bump allocator (256B aligned) ----
    char* wp = (char*)d_ws;
    auto alloc = [&](size_t bytes) { char* r = wp; wp += (bytes + 255) & ~(size_t)255; return r; };
    float* dinv   = (float*)alloc((size_t)n * 4);
    int*   cnt    = (int*)alloc((size_t)n * 4);       // becomes CSR cursor in-place
    int*   off    = (int*)alloc((size_t)(n + 1) * 4);
    int*   bsums  = (int*)alloc(1024);
    int*   bsums2 = (int*)alloc(1024);
    int*   csrs   = (int*)alloc((size_t)e * 4);
    float* csrw   = (float*)alloc((size_t)e * 4);
    int*   flags  = (int*)alloc(2048 * 4);
    int*   numUsers = (int*)alloc(256);
    int*   mCnt   = (int*)alloc(256);
    int*   used   = (int*)alloc((size_t)n * 4);
    int*   list   = (int*)alloc((size_t)MAXM * 4);
    float* bufA   = (float*)alloc((size_t)n * HDIM * 4);   // A1
    float* bufB   = (float*)alloc((size_t)n * HDIM * 4);   // P1 (first half), then h_full
    float* P2c    = (float*)alloc((size_t)MAXM * HDIM * 4);
    float* P1     = bufB;   // n*64 floats = first half of bufB

    const int nb_n = (n + 255) / 256;
    const int nb_scan = (n + 1023) / 1024;       // 196
    const int nb_g1 = (n + 3) / 4;               // 50000
    const int nb_g2 = (MAXM + 3) / 4;            // 16896
    const int nb_gemm1 = (n + 127) / 128;        // 1563
    const int nb_gemm2 = (MAXM + 127) / 128;     // 528

    // degree + CSR build
    hipLaunchKernelGGL(init_kernel, dim3(nb_n), dim3(256), 0, stream, cnt, flags, used, off, n, e);
    hipLaunchKernelGGL(hist_kernel, dim3(2500), dim3(256), 0, stream, dstp, cnt, e);
    hipLaunchKernelGGL(dinv_kernel, dim3(nb_n), dim3(256), 0, stream, cnt, dinv, n);
    hipLaunchKernelGGL(scan_blocksums, dim3(nb_scan), dim3(256), 0, stream, cnt, bsums, n);
    hipLaunchKernelGGL(scan_top, dim3(1), dim3(256), 0, stream, bsums, nb_scan, (int*)nullptr);
    hipLaunchKernelGGL(scan_final, dim3(nb_scan), dim3(256), 0, stream, cnt, bsums, off, cnt, n);
    hipLaunchKernelGGL(build_csr, dim3(2500), dim3(256), 0, stream,
                       srcp, dstp, dinv, cnt, csrs, csrw, e);

    // num_users + used-node compaction
    hipLaunchKernelGGL(mark_kernel, dim3((b + 255) / 256), dim3(256), 0, stream, items, flags, b);
    hipLaunchKernelGGL(count_kernel, dim3(1), dim3(256), 0, stream, flags, numUsers, n);
    hipLaunchKernelGGL(mark_used, dim3((b + 255) / 256), dim3(256), 0, stream,
                       users, items, numUsers, used, b, n);
    hipLaunchKernelGGL(scan_blocksums, dim3(nb_scan), dim3(256), 0, stream, used, bsums2, n);
    hipLaunchKernelGGL(scan_top, dim3(1), dim3(256), 0, stream, bsums2, nb_scan, mCnt);
    hipLaunchKernelGGL(compact_emit, dim3(nb_scan), dim3(256), 0, stream, used, bsums2, list, n);

    // conv1 (all nodes): P1 = Agg(x); A1 = relu(P1@W1 + b1)
    hipLaunchKernelGGL(gather_pre64, dim3(nb_g1), dim3(256), 0, stream,
                       off, csrs, csrw, dinv, x, P1, n);
    hipLaunchKernelGGL((gemm_tile<64, true, false>), dim3(nb_gemm1), dim3(256), 0, stream,
                       P1, W1, b1, bufA, (const int*)nullptr, (const int*)nullptr, n);

    // conv2 (used nodes only): P2c[i] = Agg(A1, list[i]); h[list[i]] = P2c[i]@W2 + b2
    hipLaunchKernelGGL(gather_pre128_list, dim3(nb_g2), dim3(256), 0, stream,
                       off, csrs, csrw, dinv, bufA, list, mCnt, P2c);
    hipLaunchKernelGGL((gemm_tile<128, false, true>), dim3(nb_gemm2), dim3(256), 0, stream,
                       P2c, W2, b2, bufB, list, mCnt, n);

    // gather + MLP + sigmoid
    hipLaunchKernelGGL(mlp_kernel, dim3(2048), dim3(256), 0, stream,
                       bufB, users, items, numUsers, fc1w, fc1b, fc2w, fc2b,
                       outw, outb, (float*)d_out, b);
}

// Round 13
// 417.498 us; speedup vs baseline: 1.5739x; 1.0996x over previous
//
#include <hip/hip_runtime.h>
#include <math.h>

// ---------------------------------------------------------------------------
// TemporalGNN round 13: round-12 profile = 459us, top-5 all mlp_kernel
// (88.5us, VALUBusy 48%, occ 40%): wave-serial fc1 re-streams 64KB fc1w
// from L1/L2 per 8-row tile at 1.6 FMA/float. Rewrite MLP as register-
// blocked GEMM (gemm_tile structure): 128 rows x 64 cols/block, 8x4
// thread tile, gather fused into transposed z staging, fc1w chunked in
// LDS, a1 in LDS (overlay), fc2w register-resident. All other kernels
// unchanged from round 12.
// ws: dinv|cnt|off|bsums|bsums2|csr_src|csr_w|flags|numUsers|mCnt|used|list|
//     bufA(A1: n*128)|bufB(P1 first half, later h_full: n*128)|P2c(67584*128)
// ---------------------------------------------------------------------------

#define HDIM 128
#define MAXM 67584   // 65536 users + 2048 items upper bound

__global__ __launch_bounds__(256) void init_kernel(int* __restrict__ cnt,
                                                   int* __restrict__ flags,
                                                   int* __restrict__ used,
                                                   int* __restrict__ off, int n, int e) {
    int i = blockIdx.x * 256 + threadIdx.x;
    if (i < n) { cnt[i] = 0; used[i] = 0; }
    if (i < 2048) flags[i] = 0;
    if (i == 0) off[n] = e;
}

__global__ __launch_bounds__(256) void hist_kernel(const int* __restrict__ dst,
                                                   int* __restrict__ cnt, int e) {
    int i = blockIdx.x * 256 + threadIdx.x;
    int stride = gridDim.x * 256;
    for (; i < e; i += stride) atomicAdd(&cnt[dst[i]], 1);
}

__global__ __launch_bounds__(256) void dinv_kernel(const int* __restrict__ cnt,
                                                   float* __restrict__ dinv, int n) {
    int i = blockIdx.x * 256 + threadIdx.x;
    if (i < n) dinv[i] = rsqrtf((float)cnt[i] + 1.0f);  // +1 = self-loop
}

// ---- generic 1024-per-block scan helpers ----
__global__ __launch_bounds__(256) void scan_blocksums(const int* __restrict__ v,
                                                      int* __restrict__ bsums, int n) {
    int base = blockIdx.x * 1024, t = threadIdx.x;
    int s = 0;
#pragma unroll
    for (int j = 0; j < 4; ++j) { int i = base + t * 4 + j; if (i < n) s += v[i]; }
    __shared__ int red[256];
    red[t] = s; __syncthreads();
    for (int o = 128; o; o >>= 1) { if (t < o) red[t] += red[t + o]; __syncthreads(); }
    if (t == 0) bsums[blockIdx.x] = red[0];
}

__global__ __launch_bounds__(256) void scan_top(int* __restrict__ bsums, int nb,
                                                int* __restrict__ total) {
    __shared__ int sh[256];
    int t = threadIdx.x;
    int v = (t < nb) ? bsums[t] : 0;
    sh[t] = v; __syncthreads();
    for (int o = 1; o < 256; o <<= 1) {
        int u = (t >= o) ? sh[t - o] : 0;
        __syncthreads();
        sh[t] += u;
        __syncthreads();
    }
    if (t < nb) bsums[t] = sh[t] - v;  // exclusive
    if (total && t == nb - 1) *total = sh[t];
}

__global__ __launch_bounds__(256) void scan_final(const int* __restrict__ cnt,
                                                  const int* __restrict__ bsums,
                                                  int* __restrict__ off,
                                                  int* cursor, int n) {
    int base = blockIdx.x * 1024, t = threadIdx.x;
    int v[4]; int s = 0;
#pragma unroll
    for (int j = 0; j < 4; ++j) { int i = base + t * 4 + j; v[j] = (i < n) ? cnt[i] : 0; s += v[j]; }
    __shared__ int sh[256];
    sh[t] = s; __syncthreads();
    for (int o = 1; o < 256; o <<= 1) {
        int u = (t >= o) ? sh[t - o] : 0;
        __syncthreads();
        sh[t] += u;
        __syncthreads();
    }
    int p = bsums[blockIdx.x] + (sh[t] - s);
#pragma unroll
    for (int j = 0; j < 4; ++j) {
        int i = base + t * 4 + j;
        if (i < n) { off[i] = p; cursor[i] = p; p += v[j]; }
    }
}

// compact: list[prefix(used)[i]] = i for used[i]!=0
__global__ __launch_bounds__(256) void compact_emit(const int* __restrict__ used,
                                                    const int* __restrict__ bsums,
                                                    int* __restrict__ list, int n) {
    int base = blockIdx.x * 1024, t = threadIdx.x;
    int v[4]; int s = 0;
#pragma unroll
    for (int j = 0; j < 4; ++j) { int i = base + t * 4 + j; v[j] = (i < n) ? used[i] : 0; s += v[j]; }
    __shared__ int sh[256];
    sh[t] = s; __syncthreads();
    for (int o = 1; o < 256; o <<= 1) {
        int u = (t >= o) ? sh[t - o] : 0;
        __syncthreads();
        sh[t] += u;
        __syncthreads();
    }
    int p = bsums[blockIdx.x] + (sh[t] - s);
#pragma unroll
    for (int j = 0; j < 4; ++j) {
        int i = base + t * 4 + j;
        if (i < n && v[j]) { list[p] = i; }
        p += v[j];
    }
}

__global__ __launch_bounds__(256) void build_csr(const int* __restrict__ src,
                                                 const int* __restrict__ dst,
                                                 const float* __restrict__ dinv,
                                                 int* __restrict__ cursor,
                                                 int* __restrict__ csr_src,
                                                 float* __restrict__ csr_w, int e) {
    int i = blockIdx.x * 256 + threadIdx.x;
    int stride = gridDim.x * 256;
    for (; i < e; i += stride) {
        int s = src[i], d = dst[i];
        int p = atomicAdd(&cursor[d], 1);
        csr_src[p] = s;
        csr_w[p] = dinv[s] * dinv[d];
    }
}

// ---- conv1 pre-aggregation over ALL nodes (D=64 input), 4-wide batched ----
__global__ __launch_bounds__(256) void gather_pre64(const int* __restrict__ off,
                                                    const int* __restrict__ csr_src,
                                                    const float* __restrict__ csr_w,
                                                    const float* __restrict__ dinv,
                                                    const float* __restrict__ X,
                                                    float* __restrict__ P, int n) {
    const int lane = threadIdx.x & 63;
    const int d = blockIdx.x * 4 + (threadIdx.x >> 6);
    if (d >= n) return;
    const float di = dinv[d];
    const float sl = di * di;
    const int p0 = off[d], p1 = off[d + 1];

    float a = X[(size_t)d * 64 + lane] * sl;

    int p = p0;
    for (; p + 4 <= p1; p += 4) {
        int s0 = csr_src[p + 0], s1 = csr_src[p + 1];
        int s2 = csr_src[p + 2], s3 = csr_src[p + 3];
        float w0 = csr_w[p + 0], w1 = csr_w[p + 1];
        float w2 = csr_w[p + 2], w3 = csr_w[p + 3];
        float v0 = X[(size_t)s0 * 64 + lane];
        float v1 = X[(size_t)s1 * 64 + lane];
        float v2 = X[(size_t)s2 * 64 + lane];
        float v3 = X[(size_t)s3 * 64 + lane];
        a = fmaf(v0, w0, a);
        a = fmaf(v1, w1, a);
        a = fmaf(v2, w2, a);
        a = fmaf(v3, w3, a);
    }
    if (p + 2 <= p1) {
        int s0 = csr_src[p + 0], s1 = csr_src[p + 1];
        float w0 = csr_w[p + 0], w1 = csr_w[p + 1];
        float v0 = X[(size_t)s0 * 64 + lane];
        float v1 = X[(size_t)s1 * 64 + lane];
        a = fmaf(v0, w0, a);
        a = fmaf(v1, w1, a);
        p += 2;
    }
    if (p < p1) {
        a = fmaf(X[(size_t)csr_src[p] * 64 + lane], csr_w[p], a);
    }
    P[(size_t)d * 64 + lane] = a;
}

// ---- conv2 pre-aggregation over USED nodes only (D=128), 4-wide batched ----
__global__ __launch_bounds__(256) void gather_pre128_list(const int* __restrict__ off,
                                                          const int* __restrict__ csr_src,
                                                          const float* __restrict__ csr_w,
                                                          const float* __restrict__ dinv,
                                                          const float* __restrict__ X,
                                                          const int* __restrict__ list,
                                                          const int* __restrict__ mPtr,
                                                          float* __restrict__ Pc) {
    const int lane = threadIdx.x & 63;
    const int i = blockIdx.x * 4 + (threadIdx.x >> 6);
    if (i >= *mPtr) return;
    const int d = list[i];
    const float di = dinv[d];
    const float sl = di * di;
    const int p0 = off[d], p1 = off[d + 1];
    const float2* X2 = (const float2*)X;

    float2 a = X2[(size_t)d * 64 + lane];
    a.x *= sl; a.y *= sl;

    int p = p0;
    for (; p + 4 <= p1; p += 4) {
        int s0 = csr_src[p + 0], s1 = csr_src[p + 1];
        int s2 = csr_src[p + 2], s3 = csr_src[p + 3];
        float w0 = csr_w[p + 0], w1 = csr_w[p + 1];
        float w2 = csr_w[p + 2], w3 = csr_w[p + 3];
        float2 v0 = X2[(size_t)s0 * 64 + lane];
        float2 v1 = X2[(size_t)s1 * 64 + lane];
        float2 v2 = X2[(size_t)s2 * 64 + lane];
        float2 v3 = X2[(size_t)s3 * 64 + lane];
        a.x = fmaf(v0.x, w0, a.x); a.y = fmaf(v0.y, w0, a.y);
        a.x = fmaf(v1.x, w1, a.x); a.y = fmaf(v1.y, w1, a.y);
        a.x = fmaf(v2.x, w2, a.x); a.y = fmaf(v2.y, w2, a.y);
        a.x = fmaf(v3.x, w3, a.x); a.y = fmaf(v3.y, w3, a.y);
    }
    if (p + 2 <= p1) {
        int s0 = csr_src[p + 0], s1 = csr_src[p + 1];
        float w0 = csr_w[p + 0], w1 = csr_w[p + 1];
        float2 v0 = X2[(size_t)s0 * 64 + lane];
        float2 v1 = X2[(size_t)s1 * 64 + lane];
        a.x = fmaf(v0.x, w0, a.x); a.y = fmaf(v0.y, w0, a.y);
        a.x = fmaf(v1.x, w1, a.x); a.y = fmaf(v1.y, w1, a.y);
        p += 2;
    }
    if (p < p1) {
        float w = csr_w[p];
        float2 v = X2[(size_t)csr_src[p] * 64 + lane];
        a.x = fmaf(v.x, w, a.x); a.y = fmaf(v.y, w, a.y);
    }
    ((float2*)Pc)[(size_t)i * 64 + lane] = a;
}

// ---- register-blocked GEMM: out = X @ W + bias (unchanged from r12) ----
template <int K, bool RELU, bool SCATTER>
__global__ __launch_bounds__(256, 3) void gemm_tile(const float* __restrict__ X,
                                                    const float* __restrict__ W,
                                                    const float* __restrict__ bias,
                                                    float* __restrict__ out,
                                                    const int* __restrict__ rowlist,
                                                    const int* __restrict__ mPtr,
                                                    int n) {
    __shared__ float xt[32][128];   // 16 KB, transposed X chunk
    __shared__ float wl[32][128];   // 16 KB, W chunk

    const int m = SCATTER ? *mPtr : n;
    const int rowBase = blockIdx.x * 128;
    if (rowBase >= m) return;

    const int tid = threadIdx.x;
    const int tx = tid & 15;        // col group (8 cols)
    const int tyg = tid >> 4;       // row group (8 rows)

    const int srow = tid >> 1;            // staging: row 0..127
    const int scol = (tid & 1) * 16;      // staging: col half
    const int grow = rowBase + srow;
    const bool valid = grow < m;

    float acc[8][8] = {};

    for (int chunk = 0; chunk < K / 32; ++chunk) {
        __syncthreads();
#pragma unroll
        for (int q = 0; q < 4; ++q) {
            int c = scol + q * 4;
            float4 v = {0.f, 0.f, 0.f, 0.f};
            if (valid) v = *(const float4*)&X[(size_t)grow * K + chunk * 32 + c];
            xt[c + 0][srow] = v.x;
            xt[c + 1][srow] = v.y;
            xt[c + 2][srow] = v.z;
            xt[c + 3][srow] = v.w;
        }
        {
            const float4* Ws = (const float4*)(W + (size_t)chunk * 32 * 128);
            float4* wl4 = (float4*)wl;
#pragma unroll
            for (int q = 0; q < 4; ++q) wl4[tid + q * 256] = Ws[tid + q * 256];
        }
        __syncthreads();

#pragma unroll 2
        for (int k = 0; k < 32; ++k) {
            float4 xa = *(const float4*)&xt[k][tyg * 8];
            float4 xb = *(const float4*)&xt[k][tyg * 8 + 4];
            float4 wa = *(const float4*)&wl[k][tx * 8];
            float4 wb = *(const float4*)&wl[k][tx * 8 + 4];
            float xv[8] = {xa.x, xa.y, xa.z, xa.w, xb.x, xb.y, xb.z, xb.w};
            float wv[8] = {wa.x, wa.y, wa.z, wa.w, wb.x, wb.y, wb.z, wb.w};
#pragma unroll
            for (int i = 0; i < 8; ++i)
#pragma unroll
                for (int j = 0; j < 8; ++j)
                    acc[i][j] = fmaf(xv[i], wv[j], acc[i][j]);
        }
    }

    float4 bv0 = *(const float4*)&bias[tx * 8];
    float4 bv1 = *(const float4*)&bias[tx * 8 + 4];
    float bv[8] = {bv0.x, bv0.y, bv0.z, bv0.w, bv1.x, bv1.y, bv1.z, bv1.w};

#pragma unroll
    for (int i = 0; i < 8; ++i) {
        int r = rowBase + tyg * 8 + i;
        if (r < m) {
            float o[8];
#pragma unroll
            for (int j = 0; j < 8; ++j) {
                o[j] = acc[i][j] + bv[j];
                if (RELU) o[j] = fmaxf(o[j], 0.f);
            }
            int orow = SCATTER ? rowlist[r] : r;
            float* op = out + (size_t)orow * HDIM + tx * 8;
            *(float4*)op = {o[0], o[1], o[2], o[3]};
            *(float4*)(op + 4) = {o[4], o[5], o[6], o[7]};
        }
    }
}

__global__ __launch_bounds__(256) void mark_kernel(const int* __restrict__ items,
                                                   int* __restrict__ flags, int b) {
    int i = blockIdx.x * 256 + threadIdx.x;
    if (i < b) flags[items[i]] = 1;
}

__global__ __launch_bounds__(256) void count_kernel(const int* __restrict__ flags,
                                                    int* __restrict__ numUsers, int n) {
    __shared__ int sred[4];
    int tid = threadIdx.x;
    int s = 0;
    for (int i = tid; i < 2048; i += 256) s += flags[i];
    for (int m = 32; m; m >>= 1) s += __shfl_xor(s, m, 64);
    if ((tid & 63) == 0) sred[tid >> 6] = s;
    __syncthreads();
    if (tid == 0) *numUsers = n - (sred[0] + sred[1] + sred[2] + sred[3]);
}

__global__ __launch_bounds__(256) void mark_used(const int* __restrict__ users,
                                                 const int* __restrict__ items,
                                                 const int* __restrict__ nuPtr,
                                                 int* __restrict__ used, int b, int n) {
    int i = blockIdx.x * 256 + threadIdx.x;
    if (i < b) {
        used[users[i]] = 1;
        int idx = *nuPtr + items[i];
        if (idx < n) used[idx] = 1;
    }
}

// ---- fused MLP: gather z -> fc1 (GEMM-style) -> fc2 -> out -> sigmoid ----
// Block: 128 batch rows x 64 fc1 cols; thread (tyg,tx) = 8 rows x 4 cols.
// z tile staged TRANSPOSED from h[user]/h[item] rows (gather fused into
// staging); fc1w chunked in LDS; a1 in LDS (overlay, padded to 68);
// fc2w register-resident (64 VGPR, col-owned).
#define MTILE 128
__global__ __launch_bounds__(256) void mlp_kernel(
    const float* __restrict__ h, const int* __restrict__ users,
    const int* __restrict__ items, const int* __restrict__ numUsersPtr,
    const float* __restrict__ fc1w, const float* __restrict__ fc1b,
    const float* __restrict__ fc2w, const float* __restrict__ fc2b,
    const float* __restrict__ outw, const float* __restrict__ outb,
    float* __restrict__ out, int bsize) {
    __shared__ float smem[MTILE * 68];   // 34816 B; zt[32][128]+wt[32][64] overlay a1[128][68]
    float* zt = smem;           // 4096 floats
    float* wt = smem + 4096;    // 2048 floats
    float* a1 = smem;           // 8704 floats

    const int tid = threadIdx.x;
    const int base = blockIdx.x * MTILE;
    const int nu = *numUsersPtr;

    // staging role: row = tid>>1 (0..127), col half = (tid&1)*16
    const int srow = tid >> 1;
    const int scol = (tid & 1) * 16;
    int gr = base + srow; if (gr >= bsize) gr = bsize - 1;
    const int urow = users[gr];
    const int irow = nu + items[gr];

    // compute role: 8 rows x 4 cols
    const int tx = tid & 15;
    const int tyg = tid >> 4;

    float acc[8][4] = {};

    for (int c = 0; c < 8; ++c) {
        __syncthreads();
        // z chunk: k in [c*32, c*32+32); k<128 -> user row, else item row
        const float* src = (c < 4) ? (h + (size_t)urow * HDIM + c * 32)
                                   : (h + (size_t)irow * HDIM + (c - 4) * 32);
#pragma unroll
        for (int q = 0; q < 4; ++q) {
            int cc = scol + q * 4;
            float4 v = *(const float4*)&src[cc];
            zt[(cc + 0) * 128 + srow] = v.x;
            zt[(cc + 1) * 128 + srow] = v.y;
            zt[(cc + 2) * 128 + srow] = v.z;
            zt[(cc + 3) * 128 + srow] = v.w;
        }
        // fc1w chunk [32][64] linear
        {
            const float4* Ws = (const float4*)(fc1w + c * 32 * 64);
            float4* wt4 = (float4*)wt;
            wt4[tid] = Ws[tid];
            wt4[tid + 256] = Ws[tid + 256];
        }
        __syncthreads();

#pragma unroll 4
        for (int k = 0; k < 32; ++k) {
            float4 za = *(const float4*)&zt[k * 128 + tyg * 8];
            float4 zb = *(const float4*)&zt[k * 128 + tyg * 8 + 4];
            float4 w = *(const float4*)&wt[k * 64 + tx * 4];
            float zv[8] = {za.x, za.y, za.z, za.w, zb.x, zb.y, zb.z, zb.w};
            float wv[4] = {w.x, w.y, w.z, w.w};
#pragma unroll
            for (int i = 0; i < 8; ++i)
#pragma unroll
                for (int j = 0; j < 4; ++j)
                    acc[i][j] = fmaf(zv[i], wv[j], acc[i][j]);
        }
    }

    __syncthreads();   // zt/wt dead; overlay a1
    {
        float4 bv = *(const float4*)&fc1b[tx * 4];
#pragma unroll
        for (int i = 0; i < 8; ++i) {
            float4 o;
            o.x = fmaxf(acc[i][0] + bv.x, 0.f);
            o.y = fmaxf(acc[i][1] + bv.y, 0.f);
            o.z = fmaxf(acc[i][2] + bv.z, 0.f);
            o.w = fmaxf(acc[i][3] + bv.w, 0.f);
            *(float4*)&a1[(tyg * 8 + i) * 68 + tx * 4] = o;
        }
    }
    __syncthreads();

    // fc2 (64->32) + relu + out (32->1) + sigmoid. 32 rows per wave.
    const int lane = tid & 63;
    const int wid = tid >> 6;
    const int half = lane >> 5;
    const int j = lane & 31;
    float w2[64];
#pragma unroll
    for (int o = 0; o < 64; ++o) w2[o] = fc2w[o * 32 + j];
    const float ow = outw[j];
    const float b2j = fc2b[j];
    const float ob = outb[0];

    for (int rp = 0; rp < 32; rp += 2) {
        int rl = wid * 32 + rp + half;
        float s = b2j;
#pragma unroll
        for (int oq = 0; oq < 16; ++oq) {
            float4 av = *(const float4*)&a1[rl * 68 + oq * 4];
            s = fmaf(av.x, w2[oq * 4 + 0], s);
            s = fmaf(av.y, w2[oq * 4 + 1], s);
            s = fmaf(av.z, w2[oq * 4 + 2], s);
            s = fmaf(av.w, w2[oq * 4 + 3], s);
        }
        float p = fmaxf(s, 0.f) * ow;
#pragma unroll
        for (int mm = 16; mm; mm >>= 1) p += __shfl_xor(p, mm, 32);
        if (j == 0) {
            int row = base + rl;
            if (row < bsize) out[row] = 1.f / (1.f + expf(-(p + ob)));
        }
    }
}

extern "C" void kernel_launch(void* const* d_in, const int* in_sizes, int n_in,
                              void* d_out, int out_size, void* d_ws, size_t ws_size,
                              hipStream_t stream) {
    const float* x = (const float*)d_in[0];
    const float* W1 = (const float*)d_in[1];
    const float* b1 = (const float*)d_in[2];
    const float* W2 = (const float*)d_in[3];
    const float* b2 = (const float*)d_in[4];
    const float* fc1w = (const float*)d_in[5];
    const float* fc1b = (const float*)d_in[6];
    const float* fc2w = (const float*)d_in[7];
    const float* fc2b = (const float*)d_in[8];
    const float* outw = (const float*)d_in[9];
    const float* outb = (const float*)d_in[10];
    const int* ei = (const int*)d_in[11];
    const int* users = (const int*)d_in[12];
    const int* items = (const int*)d_in[13];

    const int n = in_sizes[0] / 64;   // 200000
    const int e = in_sizes[11] / 2;   // 640000
    const int b = in_sizes[12];       // 65536

    const int* srcp = ei;
    const int* dstp = ei + e;

    // ---- workspace bump allocator (256B aligned) ----
    char* wp = (char*)d_ws;
    auto alloc = [&](size_t bytes) { char* r = wp; wp += (bytes + 255) & ~(size_t)255; return r; };
    float* dinv   = (float*)alloc((size_t)n * 4);
    int*   cnt    = (int*)alloc((size_t)n * 4);       // becomes CSR cursor in-place
    int*   off    = (int*)alloc((size_t)(n + 1) * 4);
    int*   bsums  = (int*)alloc(1024);
    int*   bsums2 = (int*)alloc(1024);
    int*   csrs   = (int*)alloc((size_t)e * 4);
    float* csrw   = (float*)alloc((size_t)e * 4);
    int*   flags  = (int*)alloc(2048 * 4);
    int*   numUsers = (int*)alloc(256);
    int*   mCnt   = (int*)alloc(256);
    int*   used   = (int*)alloc((size_t)n * 4);
    int*   list   = (int*)alloc((size_t)MAXM * 4);
    float* bufA   = (float*)alloc((size_t)n * HDIM * 4);   // A1
    float* bufB   = (float*)alloc((size_t)n * HDIM * 4);   // P1 (first half), then h_full
    float* P2c    = (float*)alloc((size_t)MAXM * HDIM * 4);
    float* P1     = bufB;   // n*64 floats = first half of bufB

    const int nb_n = (n + 255) / 256;
    const int nb_scan = (n + 1023) / 1024;       // 196
    const int nb_g1 = (n + 3) / 4;               // 50000
    const int nb_g2 = (MAXM + 3) / 4;            // 16896
    const int nb_gemm1 = (n + 127) / 128;        // 1563
    const int nb_gemm2 = (MAXM + 127) / 128;     // 528
    const int nb_mlp = (b + MTILE - 1) / MTILE;  // 512

    // degree + CSR build
    hipLaunchKernelGGL(init_kernel, dim3(nb_n), dim3(256), 0, stream, cnt, flags, used, off, n, e);
    hipLaunchKernelGGL(hist_kernel, dim3(2500), dim3(256), 0, stream, dstp, cnt, e);
    hipLaunchKernelGGL(dinv_kernel, dim3(nb_n), dim3(256), 0, stream, cnt, dinv, n);
    hipLaunchKernelGGL(scan_blocksums, dim3(nb_scan), dim3(256), 0, stream, cnt, bsums, n);
    hipLaunchKernelGGL(scan_top, dim3(1), dim3(256), 0, stream, bsums, nb_scan, (int*)nullptr);
    hipLaunchKernelGGL(scan_final, dim3(nb_scan), dim3(256), 0, stream, cnt, bsums, off, cnt, n);
    hipLaunchKernelGGL(build_csr, dim3(2500), dim3(256), 0, stream,
                       srcp, dstp, dinv, cnt, csrs, csrw, e);

    // num_users + used-node compaction
    hipLaunchKernelGGL(mark_kernel, dim3((b + 255) / 256), dim3(256), 0, stream, items, flags, b);
    hipLaunchKernelGGL(count_kernel, dim3(1), dim3(256), 0, stream, flags, numUsers, n);
    hipLaunchKernelGGL(mark_used, dim3((b + 255) / 256), dim3(256), 0, stream,
                       users, items, numUsers, used, b, n);
    hipLaunchKernelGGL(scan_blocksums, dim3(nb_scan), dim3(256), 0, stream, used, bsums2, n);
    hipLaunchKernelGGL(scan_top, dim3(1), dim3(256), 0, stream, bsums2, nb_scan, mCnt);
    hipLaunchKernelGGL(compact_emit, dim3(nb_scan), dim3(256), 0, stream, used, bsums2, list, n);

    // conv1 (all nodes): P1 = Agg(x); A1 = relu(P1@W1 + b1)
    hipLaunchKernelGGL(gather_pre64, dim3(nb_g1), dim3(256), 0, stream,
                       off, csrs, csrw, dinv, x, P1, n);
    hipLaunchKernelGGL((gemm_tile<64, true, false>), dim3(nb_gemm1), dim3(256), 0, stream,
                       P1, W1, b1, bufA, (const int*)nullptr, (const int*)nullptr, n);

    // conv2 (used nodes only): P2c[i] = Agg(A1, list[i]); h[list[i]] = P2c[i]@W2 + b2
    hipLaunchKernelGGL(gather_pre128_list, dim3(nb_g2), dim3(256), 0, stream,
                       off, csrs, csrw, dinv, bufA, list, mCnt, P2c);
    hipLaunchKernelGGL((gemm_tile<128, false, true>), dim3(nb_gemm2), dim3(256), 0, stream,
                       P2c, W2, b2, bufB, list, mCnt, n);

    // fused gather + MLP + sigmoid
    hipLaunchKernelGGL(mlp_kernel, dim3(nb_mlp), dim3(256), 0, stream,
                       bufB, users, items, numUsers, fc1w, fc1b, fc2w, fc2b,
                       outw, outb, (float*)d_out, b);
}

// Round 15
// 390.961 us; speedup vs baseline: 1.6808x; 1.0679x over previous
//
#include <hip/hip_runtime.h>
#include <math.h>

// ---------------------------------------------------------------------------
// TemporalGNN round 15 == round 14 resubmit (round-14 bench died to
// GPUAcquisitionTimeout infra failure; source unbenched).
// Round-13 profile: 417us, top-5 all gather_pre64 (80us, VALUBusy 18%,
// HBM 26% — still latency-bound; avg degree 3.2 made the 4-wide edge
// batch mostly dead code). Fix: multi-node waves with float4 lanes —
// 16 lanes/node (1 float4 each) -> 4 nodes/wave in gather_pre64
// (16 row-loads in flight/wave, 4x fewer VMEM instrs); same for
// gather_pre128_list (2 float4/lane). All other kernels unchanged.
// ws: dinv|cnt|off|bsums|bsums2|csr_src|csr_w|flags|numUsers|mCnt|used|list|
//     bufA(A1: n*128)|bufB(P1 first half, later h_full: n*128)|P2c(67584*128)
// ---------------------------------------------------------------------------

#define HDIM 128
#define MAXM 67584   // 65536 users + 2048 items upper bound

__global__ __launch_bounds__(256) void init_kernel(int* __restrict__ cnt,
                                                   int* __restrict__ flags,
                                                   int* __restrict__ used,
                                                   int* __restrict__ off, int n, int e) {
    int i = blockIdx.x * 256 + threadIdx.x;
    if (i < n) { cnt[i] = 0; used[i] = 0; }
    if (i < 2048) flags[i] = 0;
    if (i == 0) off[n] = e;
}

__global__ __launch_bounds__(256) void hist_kernel(const int* __restrict__ dst,
                                                   int* __restrict__ cnt, int e) {
    int i = blockIdx.x * 256 + threadIdx.x;
    int stride = gridDim.x * 256;
    for (; i < e; i += stride) atomicAdd(&cnt[dst[i]], 1);
}

__global__ __launch_bounds__(256) void dinv_kernel(const int* __restrict__ cnt,
                                                   float* __restrict__ dinv, int n) {
    int i = blockIdx.x * 256 + threadIdx.x;
    if (i < n) dinv[i] = rsqrtf((float)cnt[i] + 1.0f);  // +1 = self-loop
}

// ---- generic 1024-per-block scan helpers ----
__global__ __launch_bounds__(256) void scan_blocksums(const int* __restrict__ v,
                                                      int* __restrict__ bsums, int n) {
    int base = blockIdx.x * 1024, t = threadIdx.x;
    int s = 0;
#pragma unroll
    for (int j = 0; j < 4; ++j) { int i = base + t * 4 + j; if (i < n) s += v[i]; }
    __shared__ int red[256];
    red[t] = s; __syncthreads();
    for (int o = 128; o; o >>= 1) { if (t < o) red[t] += red[t + o]; __syncthreads(); }
    if (t == 0) bsums[blockIdx.x] = red[0];
}

__global__ __launch_bounds__(256) void scan_top(int* __restrict__ bsums, int nb,
                                                int* __restrict__ total) {
    __shared__ int sh[256];
    int t = threadIdx.x;
    int v = (t < nb) ? bsums[t] : 0;
    sh[t] = v; __syncthreads();
    for (int o = 1; o < 256; o <<= 1) {
        int u = (t >= o) ? sh[t - o] : 0;
        __syncthreads();
        sh[t] += u;
        __syncthreads();
    }
    if (t < nb) bsums[t] = sh[t] - v;  // exclusive
    if (total && t == nb - 1) *total = sh[t];
}

__global__ __launch_bounds__(256) void scan_final(const int* __restrict__ cnt,
                                                  const int* __restrict__ bsums,
                                                  int* __restrict__ off,
                                                  int* cursor, int n) {
    int base = blockIdx.x * 1024, t = threadIdx.x;
    int v[4]; int s = 0;
#pragma unroll
    for (int j = 0; j < 4; ++j) { int i = base + t * 4 + j; v[j] = (i < n) ? cnt[i] : 0; s += v[j]; }
    __shared__ int sh[256];
    sh[t] = s; __syncthreads();
    for (int o = 1; o < 256; o <<= 1) {
        int u = (t >= o) ? sh[t - o] : 0;
        __syncthreads();
        sh[t] += u;
        __syncthreads();
    }
    int p = bsums[blockIdx.x] + (sh[t] - s);
#pragma unroll
    for (int j = 0; j < 4; ++j) {
        int i = base + t * 4 + j;
        if (i < n) { off[i] = p; cursor[i] = p; p += v[j]; }
    }
}

// compact: list[prefix(used)[i]] = i for used[i]!=0
__global__ __launch_bounds__(256) void compact_emit(const int* __restrict__ used,
                                                    const int* __restrict__ bsums,
                                                    int* __restrict__ list, int n) {
    int base = blockIdx.x * 1024, t = threadIdx.x;
    int v[4]; int s = 0;
#pragma unroll
    for (int j = 0; j < 4; ++j) { int i = base + t * 4 + j; v[j] = (i < n) ? used[i] : 0; s += v[j]; }
    __shared__ int sh[256];
    sh[t] = s; __syncthreads();
    for (int o = 1; o < 256; o <<= 1) {
        int u = (t >= o) ? sh[t - o] : 0;
        __syncthreads();
        sh[t] += u;
        __syncthreads();
    }
    int p = bsums[blockIdx.x] + (sh[t] - s);
#pragma unroll
    for (int j = 0; j < 4; ++j) {
        int i = base + t * 4 + j;
        if (i < n && v[j]) { list[p] = i; }
        p += v[j];
    }
}

__global__ __launch_bounds__(256) void build_csr(const int* __restrict__ src,
                                                 const int* __restrict__ dst,
                                                 const float* __restrict__ dinv,
                                                 int* __restrict__ cursor,
                                                 int* __restrict__ csr_src,
                                                 float* __restrict__ csr_w, int e) {
    int i = blockIdx.x * 256 + threadIdx.x;
    int stride = gridDim.x * 256;
    for (; i < e; i += stride) {
        int s = src[i], d = dst[i];
        int p = atomicAdd(&cursor[d], 1);
        csr_src[p] = s;
        csr_w[p] = dinv[s] * dinv[d];
    }
}

// ---- conv1 pre-aggregation over ALL nodes (D=64) ----
// 16 lanes per node (1 float4 each) -> 4 nodes/wave, 16 nodes/block.
// 4-wide edge batch: up to 16 independent row loads in flight per wave.
__global__ __launch_bounds__(256) void gather_pre64(const int* __restrict__ off,
                                                    const int* __restrict__ csr_src,
                                                    const float* __restrict__ csr_w,
                                                    const float* __restrict__ dinv,
                                                    const float* __restrict__ X,
                                                    float* __restrict__ P, int n) {
    const int l = threadIdx.x & 15;
    const int d = blockIdx.x * 16 + (threadIdx.x >> 4);
    if (d >= n) return;
    const float di = dinv[d];
    const float sl = di * di;
    const int p0 = off[d], p1 = off[d + 1];
    const float4* X4 = (const float4*)X;

    float4 a = X4[(size_t)d * 16 + l];
    a.x *= sl; a.y *= sl; a.z *= sl; a.w *= sl;

    int p = p0;
    for (; p + 4 <= p1; p += 4) {
        int s0 = csr_src[p + 0], s1 = csr_src[p + 1];
        int s2 = csr_src[p + 2], s3 = csr_src[p + 3];
        float w0 = csr_w[p + 0], w1 = csr_w[p + 1];
        float w2 = csr_w[p + 2], w3 = csr_w[p + 3];
        float4 v0 = X4[(size_t)s0 * 16 + l];
        float4 v1 = X4[(size_t)s1 * 16 + l];
        float4 v2 = X4[(size_t)s2 * 16 + l];
        float4 v3 = X4[(size_t)s3 * 16 + l];
        a.x = fmaf(v0.x, w0, a.x); a.y = fmaf(v0.y, w0, a.y);
        a.z = fmaf(v0.z, w0, a.z); a.w = fmaf(v0.w, w0, a.w);
        a.x = fmaf(v1.x, w1, a.x); a.y = fmaf(v1.y, w1, a.y);
        a.z = fmaf(v1.z, w1, a.z); a.w = fmaf(v1.w, w1, a.w);
        a.x = fmaf(v2.x, w2, a.x); a.y = fmaf(v2.y, w2, a.y);
        a.z = fmaf(v2.z, w2, a.z); a.w = fmaf(v2.w, w2, a.w);
        a.x = fmaf(v3.x, w3, a.x); a.y = fmaf(v3.y, w3, a.y);
        a.z = fmaf(v3.z, w3, a.z); a.w = fmaf(v3.w, w3, a.w);
    }
    if (p + 2 <= p1) {
        int s0 = csr_src[p + 0], s1 = csr_src[p + 1];
        float w0 = csr_w[p + 0], w1 = csr_w[p + 1];
        float4 v0 = X4[(size_t)s0 * 16 + l];
        float4 v1 = X4[(size_t)s1 * 16 + l];
        a.x = fmaf(v0.x, w0, a.x); a.y = fmaf(v0.y, w0, a.y);
        a.z = fmaf(v0.z, w0, a.z); a.w = fmaf(v0.w, w0, a.w);
        a.x = fmaf(v1.x, w1, a.x); a.y = fmaf(v1.y, w1, a.y);
        a.z = fmaf(v1.z, w1, a.z); a.w = fmaf(v1.w, w1, a.w);
        p += 2;
    }
    if (p < p1) {
        float w = csr_w[p];
        float4 v = X4[(size_t)csr_src[p] * 16 + l];
        a.x = fmaf(v.x, w, a.x); a.y = fmaf(v.y, w, a.y);
        a.z = fmaf(v.z, w, a.z); a.w = fmaf(v.w, w, a.w);
    }
    ((float4*)P)[(size_t)d * 16 + l] = a;
}

// ---- conv2 pre-aggregation over USED nodes only (D=128), compacted ----
// 16 lanes per node (2 float4 each) -> 4 nodes/wave; 4-wide edge batch.
__global__ __launch_bounds__(256) void gather_pre128_list(const int* __restrict__ off,
                                                          const int* __restrict__ csr_src,
                                                          const float* __restrict__ csr_w,
                                                          const float* __restrict__ dinv,
                                                          const float* __restrict__ X,
                                                          const int* __restrict__ list,
                                                          const int* __restrict__ mPtr,
                                                          float* __restrict__ Pc) {
    const int l = threadIdx.x & 15;
    const int i = blockIdx.x * 16 + (threadIdx.x >> 4);
    if (i >= *mPtr) return;
    const int d = list[i];
    const float di = dinv[d];
    const float sl = di * di;
    const int p0 = off[d], p1 = off[d + 1];
    const float4* X4 = (const float4*)X;

    float4 a0 = X4[(size_t)d * 32 + l];
    float4 a1 = X4[(size_t)d * 32 + 16 + l];
    a0.x *= sl; a0.y *= sl; a0.z *= sl; a0.w *= sl;
    a1.x *= sl; a1.y *= sl; a1.z *= sl; a1.w *= sl;

    int p = p0;
    for (; p + 4 <= p1; p += 4) {
        int s0 = csr_src[p + 0], s1 = csr_src[p + 1];
        int s2 = csr_src[p + 2], s3 = csr_src[p + 3];
        float w0 = csr_w[p + 0], w1 = csr_w[p + 1];
        float w2 = csr_w[p + 2], w3 = csr_w[p + 3];
        float4 u0 = X4[(size_t)s0 * 32 + l];
        float4 u1 = X4[(size_t)s1 * 32 + l];
        float4 u2 = X4[(size_t)s2 * 32 + l];
        float4 u3 = X4[(size_t)s3 * 32 + l];
        float4 q0 = X4[(size_t)s0 * 32 + 16 + l];
        float4 q1 = X4[(size_t)s1 * 32 + 16 + l];
        float4 q2 = X4[(size_t)s2 * 32 + 16 + l];
        float4 q3 = X4[(size_t)s3 * 32 + 16 + l];
        a0.x = fmaf(u0.x, w0, a0.x); a0.y = fmaf(u0.y, w0, a0.y);
        a0.z = fmaf(u0.z, w0, a0.z); a0.w = fmaf(u0.w, w0, a0.w);
        a1.x = fmaf(q0.x, w0, a1.x); a1.y = fmaf(q0.y, w0, a1.y);
        a1.z = fmaf(q0.z, w0, a1.z); a1.w = fmaf(q0.w, w0, a1.w);
        a0.x = fmaf(u1.x, w1, a0.x); a0.y = fmaf(u1.y, w1, a0.y);
        a0.z = fmaf(u1.z, w1, a0.z); a0.w = fmaf(u1.w, w1, a0.w);
        a1.x = fmaf(q1.x, w1, a1.x); a1.y = fmaf(q1.y, w1, a1.y);
        a1.z = fmaf(q1.z, w1, a1.z); a1.w = fmaf(q1.w, w1, a1.w);
        a0.x = fmaf(u2.x, w2, a0.x); a0.y = fmaf(u2.y, w2, a0.y);
        a0.z = fmaf(u2.z, w2, a0.z); a0.w = fmaf(u2.w, w2, a0.w);
        a1.x = fmaf(q2.x, w2, a1.x); a1.y = fmaf(q2.y, w2, a1.y);
        a1.z = fmaf(q2.z, w2, a1.z); a1.w = fmaf(q2.w, w2, a1.w);
        a0.x = fmaf(u3.x, w3, a0.x); a0.y = fmaf(u3.y, w3, a0.y);
        a0.z = fmaf(u3.z, w3, a0.z); a0.w = fmaf(u3.w, w3, a0.w);
        a1.x = fmaf(q3.x, w3, a1.x); a1.y = fmaf(q3.y, w3, a1.y);
        a1.z = fmaf(q3.z, w3, a1.z); a1.w = fmaf(q3.w, w3, a1.w);
    }
    for (; p < p1; ++p) {
        int s = csr_src[p];
        float w = csr_w[p];
        float4 u = X4[(size_t)s * 32 + l];
        float4 q = X4[(size_t)s * 32 + 16 + l];
        a0.x = fmaf(u.x, w, a0.x); a0.y = fmaf(u.y, w, a0.y);
        a0.z = fmaf(u.z, w, a0.z); a0.w = fmaf(u.w, w, a0.w);
        a1.x = fmaf(q.x, w, a1.x); a1.y = fmaf(q.y, w, a1.y);
        a1.z = fmaf(q.z, w, a1.z); a1.w = fmaf(q.w, w, a1.w);
    }
    ((float4*)Pc)[(size_t)i * 32 + l] = a0;
    ((float4*)Pc)[(size_t)i * 32 + 16 + l] = a1;
}

// ---- register-blocked GEMM: out = X @ W + bias (unchanged) ----
template <int K, bool RELU, bool SCATTER>
__global__ __launch_bounds__(256, 3) void gemm_tile(const float* __restrict__ X,
                                                    const float* __restrict__ W,
                                                    const float* __restrict__ bias,
                                                    float* __restrict__ out,
                                                    const int* __restrict__ rowlist,
                                                    const int* __restrict__ mPtr,
                                                    int n) {
    __shared__ float xt[32][128];   // 16 KB, transposed X chunk
    __shared__ float wl[32][128];   // 16 KB, W chunk

    const int m = SCATTER ? *mPtr : n;
    const int rowBase = blockIdx.x * 128;
    if (rowBase >= m) return;

    const int tid = threadIdx.x;
    const int tx = tid & 15;        // col group (8 cols)
    const int tyg = tid >> 4;       // row group (8 rows)

    const int srow = tid >> 1;            // staging: row 0..127
    const int scol = (tid & 1) * 16;      // staging: col half
    const int grow = rowBase + srow;
    const bool valid = grow < m;

    float acc[8][8] = {};

    for (int chunk = 0; chunk < K / 32; ++chunk) {
        __syncthreads();
#pragma unroll
        for (int q = 0; q < 4; ++q) {
            int c = scol + q * 4;
            float4 v = {0.f, 0.f, 0.f, 0.f};
            if (valid) v = *(const float4*)&X[(size_t)grow * K + chunk * 32 + c];
            xt[c + 0][srow] = v.x;
            xt[c + 1][srow] = v.y;
            xt[c + 2][srow] = v.z;
            xt[c + 3][srow] = v.w;
        }
        {
            const float4* Ws = (const float4*)(W + (size_t)chunk * 32 * 128);
            float4* wl4 = (float4*)wl;
#pragma unroll
            for (int q = 0; q < 4; ++q) wl4[tid + q * 256] = Ws[tid + q * 256];
        }
        __syncthreads();

#pragma unroll 2
        for (int k = 0; k < 32; ++k) {
            float4 xa = *(const float4*)&xt[k][tyg * 8];
            float4 xb = *(const float4*)&xt[k][tyg * 8 + 4];
            float4 wa = *(const float4*)&wl[k][tx * 8];
            float4 wb = *(const float4*)&wl[k][tx * 8 + 4];
            float xv[8] = {xa.x, xa.y, xa.z, xa.w, xb.x, xb.y, xb.z, xb.w};
            float wv[8] = {wa.x, wa.y, wa.z, wa.w, wb.x, wb.y, wb.z, wb.w};
#pragma unroll
            for (int i = 0; i < 8; ++i)
#pragma unroll
                for (int j = 0; j < 8; ++j)
                    acc[i][j] = fmaf(xv[i], wv[j], acc[i][j]);
        }
    }

    float4 bv0 = *(const float4*)&bias[tx * 8];
    float4 bv1 = *(const float4*)&bias[tx * 8 + 4];
    float bv[8] = {bv0.x, bv0.y, bv0.z, bv0.w, bv1.x, bv1.y, bv1.z, bv1.w};

#pragma unroll
    for (int i = 0; i < 8; ++i) {
        int r = rowBase + tyg * 8 + i;
        if (r < m) {
            float o[8];
#pragma unroll
            for (int j = 0; j < 8; ++j) {
                o[j] = acc[i][j] + bv[j];
                if (RELU) o[j] = fmaxf(o[j], 0.f);
            }
            int orow = SCATTER ? rowlist[r] : r;
            float* op = out + (size_t)orow * HDIM + tx * 8;
            *(float4*)op = {o[0], o[1], o[2], o[3]};
            *(float4*)(op + 4) = {o[4], o[5], o[6], o[7]};
        }
    }
}

__global__ __launch_bounds__(256) void mark_kernel(const int* __restrict__ items,
                                                   int* __restrict__ flags, int b) {
    int i = blockIdx.x * 256 + threadIdx.x;
    if (i < b) flags[items[i]] = 1;
}

__global__ __launch_bounds__(256) void count_kernel(const int* __restrict__ flags,
                                                    int* __restrict__ numUsers, int n) {
    __shared__ int sred[4];
    int tid = threadIdx.x;
    int s = 0;
    for (int i = tid; i < 2048; i += 256) s += flags[i];
    for (int m = 32; m; m >>= 1) s += __shfl_xor(s, m, 64);
    if ((tid & 63) == 0) sred[tid >> 6] = s;
    __syncthreads();
    if (tid == 0) *numUsers = n - (sred[0] + sred[1] + sred[2] + sred[3]);
}

__global__ __launch_bounds__(256) void mark_used(const int* __restrict__ users,
                                                 const int* __restrict__ items,
                                                 const int* __restrict__ nuPtr,
                                                 int* __restrict__ used, int b, int n) {
    int i = blockIdx.x * 256 + threadIdx.x;
    if (i < b) {
        used[users[i]] = 1;
        int idx = *nuPtr + items[i];
        if (idx < n) used[idx] = 1;
    }
}

// ---- fused MLP (unchanged from round 13) ----
#define MTILE 128
__global__ __launch_bounds__(256) void mlp_kernel(
    const float* __restrict__ h, const int* __restrict__ users,
    const int* __restrict__ items, const int* __restrict__ numUsersPtr,
    const float* __restrict__ fc1w, const float* __restrict__ fc1b,
    const float* __restrict__ fc2w, const float* __restrict__ fc2b,
    const float* __restrict__ outw, const float* __restrict__ outb,
    float* __restrict__ out, int bsize) {
    __shared__ float smem[MTILE * 68];   // 34816 B; zt+wt overlay a1
    float* zt = smem;           // 4096 floats
    float* wt = smem + 4096;    // 2048 floats
    float* a1 = smem;           // 8704 floats

    const int tid = threadIdx.x;
    const int base = blockIdx.x * MTILE;
    const int nu = *numUsersPtr;

    const int srow = tid >> 1;
    const int scol = (tid & 1) * 16;
    int gr = base + srow; if (gr >= bsize) gr = bsize - 1;
    const int urow = users[gr];
    const int irow = nu + items[gr];

    const int tx = tid & 15;
    const int tyg = tid >> 4;

    float acc[8][4] = {};

    for (int c = 0; c < 8; ++c) {
        __syncthreads();
        const float* src = (c < 4) ? (h + (size_t)urow * HDIM + c * 32)
                                   : (h + (size_t)irow * HDIM + (c - 4) * 32);
#pragma unroll
        for (int q = 0; q < 4; ++q) {
            int cc = scol + q * 4;
            float4 v = *(const float4*)&src[cc];
            zt[(cc + 0) * 128 + srow] = v.x;
            zt[(cc + 1) * 128 + srow] = v.y;
            zt[(cc + 2) * 128 + srow] = v.z;
            zt[(cc + 3) * 128 + srow] = v.w;
        }
        {
            const float4* Ws = (const float4*)(fc1w + c * 32 * 64);
            float4* wt4 = (float4*)wt;
            wt4[tid] = Ws[tid];
            wt4[tid + 256] = Ws[tid + 256];
        }
        __syncthreads();

#pragma unroll 4
        for (int k = 0; k < 32; ++k) {
            float4 za = *(const float4*)&zt[k * 128 + tyg * 8];
            float4 zb = *(const float4*)&zt[k * 128 + tyg * 8 + 4];
            float4 w = *(const float4*)&wt[k * 64 + tx * 4];
            float zv[8] = {za.x, za.y, za.z, za.w, zb.x, zb.y, zb.z, zb.w};
            float wv[4] = {w.x, w.y, w.z, w.w};
#pragma unroll
            for (int i = 0; i < 8; ++i)
#pragma unroll
                for (int j = 0; j < 4; ++j)
                    acc[i][j] = fmaf(zv[i], wv[j], acc[i][j]);
        }
    }

    __syncthreads();   // zt/wt dead; overlay a1
    {
        float4 bv = *(const float4*)&fc1b[tx * 4];
#pragma unroll
        for (int i = 0; i < 8; ++i) {
            float4 o;
            o.x = fmaxf(acc[i][0] + bv.x, 0.f);
            o.y = fmaxf(acc[i][1] + bv.y, 0.f);
            o.z = fmaxf(acc[i][2] + bv.z, 0.f);
            o.w = fmaxf(acc[i][3] + bv.w, 0.f);
            *(float4*)&a1[(tyg * 8 + i) * 68 + tx * 4] = o;
        }
    }
    __syncthreads();

    const int lane = tid & 63;
    const int wid = tid >> 6;
    const int half = lane >> 5;
    const int j = lane & 31;
    float w2[64];
#pragma unroll
    for (int o = 0; o < 64; ++o) w2[o] = fc2w[o * 32 + j];
    const float ow = outw[j];
    const float b2j = fc2b[j];
    const float ob = outb[0];

    for (int rp = 0; rp < 32; rp += 2) {
        int rl = wid * 32 + rp + half;
        float s = b2j;
#pragma unroll
        for (int oq = 0; oq < 16; ++oq) {
            float4 av = *(const float4*)&a1[rl * 68 + oq * 4];
            s = fmaf(av.x, w2[oq * 4 + 0], s);
            s = fmaf(av.y, w2[oq * 4 + 1], s);
            s = fmaf(av.z, w2[oq * 4 + 2], s);
            s = fmaf(av.w, w2[oq * 4 + 3], s);
        }
        float p = fmaxf(s, 0.f) * ow;
#pragma unroll
        for (int mm = 16; mm; mm >>= 1) p += __shfl_xor(p, mm, 32);
        if (j == 0) {
            int row = base + rl;
            if (row < bsize) out[row] = 1.f / (1.f + expf(-(p + ob)));
        }
    }
}

extern "C" void kernel_launch(void* const* d_in, const int* in_sizes, int n_in,
                              void* d_out, int out_size, void* d_ws, size_t ws_size,
                              hipStream_t stream) {
    const float* x = (const float*)d_in[0];
    const float* W1 = (const float*)d_in[1];
    const float* b1 = (const float*)d_in[2];
    const float* W2 = (const float*)d_in[3];
    const float* b2 = (const float*)d_in[4];
    const float* fc1w = (const float*)d_in[5];
    const float* fc1b = (const float*)d_in[6];
    const float* fc2w = (const float*)d_in[7];
    const float* fc2b = (const float*)d_in[8];
    const float* outw = (const float*)d_in[9];
    const float* outb = (const float*)d_in[10];
    const int* ei = (const int*)d_in[11];
    const int* users = (const int*)d_in[12];
    const int* items = (const int*)d_in[13];

    const int n = in_sizes[0] / 64;   // 200000
    const int e = in_sizes[11] / 2;   // 640000
    const int b = in_sizes[12];       // 65536

    const int* srcp = ei;
    const int* dstp = ei + e;

    // ---- workspace bump allocator (256B aligned) ----
    char* wp = (char*)d_ws;
    auto alloc = [&](size_t bytes) { char* r = wp; wp += (bytes + 255) & ~(size_t)255; return r; };
    float* dinv   = (float*)alloc((size_t)n * 4);
    int*   cnt    = (int*)alloc((size_t)n * 4);       // becomes CSR cursor in-place
    int*   off    = (int*)alloc((size_t)(n + 1) * 4);
    int*   bsums  = (int*)alloc(1024);
    int*   bsums2 = (int*)alloc(1024);
    int*   csrs   = (int*)alloc((size_t)e * 4);
    float* csrw   = (float*)alloc((size_t)e * 4);
    int*   flags  = (int*)alloc(2048 * 4);
    int*   numUsers = (int*)alloc(256);
    int*   mCnt   = (int*)alloc(256);
    int*   used   = (int*)alloc((size_t)n * 4);
    int*   list   = (int*)alloc((size_t)MAXM * 4);
    float* bufA   = (float*)alloc((size_t)n * HDIM * 4);   // A1
    float* bufB   = (float*)alloc((size_t)n * HDIM * 4);   // P1 (first half), then h_full
    float* P2c    = (float*)alloc((size_t)MAXM * HDIM * 4);
    float* P1     = bufB;   // n*64 floats = first half of bufB

    const int nb_n = (n + 255) / 256;
    const int nb_scan = (n + 1023) / 1024;       // 196
    const int nb_g1 = (n + 15) / 16;             // 12500
    const int nb_g2 = (MAXM + 15) / 16;          // 4224
    const int nb_gemm1 = (n + 127) / 128;        // 1563
    const int nb_gemm2 = (MAXM + 127) / 128;     // 528
    const int nb_mlp = (b + MTILE - 1) / MTILE;  // 512

    // degree + CSR build
    hipLaunchKernelGGL(init_kernel, dim3(nb_n), dim3(256), 0, stream, cnt, flags, used, off, n, e);
    hipLaunchKernelGGL(hist_kernel, dim3(2500), dim3(256), 0, stream, dstp, cnt, e);
    hipLaunchKernelGGL(dinv_kernel, dim3(nb_n), dim3(256), 0, stream, cnt, dinv, n);
    hipLaunchKernelGGL(scan_blocksums, dim3(nb_scan), dim3(256), 0, stream, cnt, bsums, n);
    hipLaunchKernelGGL(scan_top, dim3(1), dim3(256), 0, stream, bsums, nb_scan, (int*)nullptr);
    hipLaunchKernelGGL(scan_final, dim3(nb_scan), dim3(256), 0, stream, cnt, bsums, off, cnt, n);
    hipLaunchKernelGGL(build_csr, dim3(2500), dim3(256), 0, stream,
                       srcp, dstp, dinv, cnt, csrs, csrw, e);

    // num_users + used-node compaction
    hipLaunchKernelGGL(mark_kernel, dim3((b + 255) / 256), dim3(256), 0, stream, items, flags, b);
    hipLaunchKernelGGL(count_kernel, dim3(1), dim3(256), 0, stream, flags, numUsers, n);
    hipLaunchKernelGGL(mark_used, dim3((b + 255) / 256), dim3(256), 0, stream,
                       users, items, numUsers, used, b, n);
    hipLaunchKernelGGL(scan_blocksums, dim3(nb_scan), dim3(256), 0, stream, used, bsums2, n);
    hipLaunchKernelGGL(scan_top, dim3(1), dim3(256), 0, stream, bsums2, nb_scan, mCnt);
    hipLaunchKernelGGL(compact_emit, dim3(nb_scan), dim3(256), 0, stream, used, bsums2, list, n);

    // conv1 (all nodes): P1 = Agg(x); A1 = relu(P1@W1 + b1)
    hipLaunchKernelGGL(gather_pre64, dim3(nb_g1), dim3(256), 0, stream,
                       off, csrs, csrw, dinv, x, P1, n);
    hipLaunchKernelGGL((gemm_tile<64, true, false>), dim3(nb_gemm1), dim3(256), 0, stream,
                       P1, W1, b1, bufA, (const int*)nullptr, (const int*)nullptr, n);

    // conv2 (used nodes only): P2c[i] = Agg(A1, list[i]); h[list[i]] = P2c[i]@W2 + b2
    hipLaunchKernelGGL(gather_pre128_list, dim3(nb_g2), dim3(256), 0, stream,
                       off, csrs, csrw, dinv, bufA, list, mCnt, P2c);
    hipLaunchKernelGGL((gemm_tile<128, false, true>), dim3(nb_gemm2), dim3(256), 0, stream,
                       P2c, W2, b2, bufB, list, mCnt, n);

    // fused gather + MLP + sigmoid
    hipLaunchKernelGGL(mlp_kernel, dim3(nb_mlp), dim3(256), 0, stream,
                       bufB, users, items, numUsers, fc1w, fc1b, fc2w, fc2b,
                       outw, outb, (float*)d_out, b);
}